// Round 13
// baseline (1703.596 us; speedup 1.0000x reference)
//
#include <hip/hip_runtime.h>
#include <math.h>

typedef unsigned short u16;
typedef unsigned int   u32;
typedef __attribute__((ext_vector_type(2))) _Float16 half2_t;

#define B_   32
#define S_   200
#define D_   128
#define T_   199
#define NG_  50            // ceil(199/4) step-groups
#define NEGV (-1e30f)

__device__ __forceinline__ float bf2f(u16 u){
  union { u32 i; float f; } v; v.i = ((u32)u) << 16; return v.f;
}
__device__ __forceinline__ u16 f2bf(float f){
  union { float f; u32 i; } v; v.f = f;
  u32 x = v.i;
  return (u16)((x + 0x7fffu + ((x >> 16) & 1u)) >> 16);   // RNE
}
__device__ __forceinline__ u16 f2h(float x){
  union { _Float16 h; u16 u; } v; v.h = (_Float16)x; return v.u;
}
__device__ __forceinline__ float h2f(u16 u){
  union { u16 u; _Float16 h; } v; v.u = u; return (float)v.h;
}
__device__ __forceinline__ u32 pkh(float lo, float hi){
  return ((u32)f2h(hi) << 16) | f2h(lo);
}
__device__ __forceinline__ float dot2f(u32 w, u32 h, float acc){
#if __has_builtin(__builtin_amdgcn_fdot2)
  union { u32 u; half2_t h2; } a, b;
  a.u = w; b.u = h;
  return __builtin_amdgcn_fdot2(a.h2, b.h2, acc, false);
#else
  union { u32 u; _Float16 f[2]; } a, b;
  a.u = w; b.u = h;
  acc = fmaf((float)a.f[0], (float)b.f[0], acc);
  return fmaf((float)a.f[1], (float)b.f[1], acc);
#endif
}
__device__ __forceinline__ float fast_sigmoid(float x){ return 1.f/(1.f+__expf(-x)); }
__device__ __forceinline__ float fast_tanh(float x){
  float e = __expf(2.f*x);
  return 1.f - 2.f/(e + 1.f);
}

// bool storage modes: 0=int32, 1=u8, 2=bf16, 3=f32
__device__ __forceinline__ int readBool(const void* p, int i, int m){
  if (m == 0) return ((const int*)p)[i] != 0;
  if (m == 1) return ((const unsigned char*)p)[i] != 0;
  if (m == 2) return ((const u16*)p)[i] != 0;
  return ((const u32*)p)[i] != 0;
}

__device__ __forceinline__ float dot128f(const float* __restrict__ w,
                                         const float* __restrict__ x){
  float acc = 0.f;
  const float4* wp = (const float4*)w;
  #pragma unroll 8
  for (int i = 0; i < 32; i++){
    float4 v = wp[i]; int k = 4*i;
    acc = fmaf(v.x, x[k],   acc);
    acc = fmaf(v.y, x[k+1], acc);
    acc = fmaf(v.z, x[k+2], acc);
    acc = fmaf(v.w, x[k+3], acc);
  }
  return acc;
}

// producer/consumer flags (cross-XCD safe: agent-scope atomics + fences)
__device__ __forceinline__ void set_flag(int* f, int tid){
  __threadfence();
  __syncthreads();
  if (tid == 0)
    __hip_atomic_store(f, 1, __ATOMIC_RELEASE, __HIP_MEMORY_SCOPE_AGENT);
}
__device__ __forceinline__ void wait_flag(int* f, int tid){
  if (tid == 0){
    while (__hip_atomic_load(f, __ATOMIC_ACQUIRE, __HIP_MEMORY_SCOPE_AGENT) == 0)
      __builtin_amdgcn_s_sleep(16);
  }
  __syncthreads();
  __threadfence();
}

// ---------------------------------------------------------------- sniffer
__global__ void k_sniff2(const u16* __restrict__ embq_raw,
                         const unsigned char* __restrict__ mask_raw,
                         int* __restrict__ flags){
  __shared__ int bad, gt1, m4, b0;
  const int tid = threadIdx.x;
  if (tid == 0){ bad = 0; gt1 = 0; m4 = 0; b0 = 0; }
  __syncthreads();
  for (int i = tid; i < 512; i += 256){
    u16 u = embq_raw[i];
    if (u){ int e = (u >> 7) & 0xFF; if (e < 0x58 || e > 0x7F) atomicAdd(&bad, 1); }
  }
  for (int i = tid; i < 1024; i += 256){
    unsigned char c = mask_raw[i];
    if (c > 1) atomicAdd(&gt1, 1);
    if (c && (i & 3)) atomicAdd(&m4, 1);
    if (c && !(i & 3)) atomicAdd(&b0, 1);
  }
  __syncthreads();
  if (tid == 0){
    flags[0] = (bad >= 16) ? 1 : 0;
    flags[1] = gt1 ? (b0 ? 2 : 3) : (m4 ? 1 : 0);
  }
}

// ---------------------------------------------------------------- convert floats -> f32
#define NCVT 23
struct CvtArgs { const void* s[NCVT]; int off[NCVT+1]; int nreal[NCVT]; };

__global__ void k_cvt(CvtArgs a, const int* __restrict__ flags, float* __restrict__ dst){
  __shared__ int f;
  if (threadIdx.x == 0) f = flags[0];
  __syncthreads();
  int gid = blockIdx.x * 256 + threadIdx.x;
  if (gid >= a.off[NCVT]) return;
  int ai = 0;
  for (int i = 1; i < NCVT; i++) if (gid >= a.off[i]) ai = i;
  int i = gid - a.off[ai];
  float v = 0.f;
  if (i < a.nreal[ai])
    v = f ? ((const float*)a.s[ai])[i] : bf2f(((const u16*)a.s[ai])[i]);
  dst[gid] = v;
}

// ---------------------------------------------------------------- prep (transposed/coalesced weights)
__global__ void k_prep(const float* __restrict__ WHH1, const float* __restrict__ WHH2,
                       const float* __restrict__ AW,   const float* __restrict__ ALW,
                       const float* __restrict__ WIH1, const float* __restrict__ WIH2,
                       const float* __restrict__ QW,
                       u16* __restrict__ WHH1h, u16* __restrict__ WHH2h,
                       u32* __restrict__ AWt,   u32* __restrict__ ALWt,
                       u32* __restrict__ WIH1t, u32* __restrict__ WIH2t,
                       float* __restrict__ QWt)
{
  const int gid0 = blockIdx.x*256 + threadIdx.x;
  const int stride = gridDim.x*256;
  for (int g = gid0; g < 49152; g += stride){
    WHH1h[g] = f2h(WHH1[g]);
    WHH2h[g] = f2h(WHH2[g]);
  }
  for (int g = gid0; g < 24576; g += stride){
    int s = g >> 13, w = g & 8191;
    int k8 = w >> 9, r = w & 511, c = r >> 2, j = r & 3;
    const float* b = AW + s*16384 + c*128 + k8*8 + 2*j;
    AWt[g] = pkh(b[0], b[1]);
  }
  for (int g = gid0; g < 8192; g += stride){
    int k8 = g >> 9, r = g & 511, c = r >> 2, j = r & 3;
    const float* b = ALW + c*128 + k8*8 + 2*j;
    ALWt[g] = pkh(b[0], b[1]);
  }
  for (int g = gid0; g < 49152; g += stride){
    int k8 = g / 1536, r = g % 1536, c = r >> 2, j = r & 3;
    const float* b = WIH1 + c*256 + k8*8 + 2*j;
    WIH1t[g] = pkh(b[0], b[1]);
  }
  for (int g = gid0; g < 24576; g += stride){
    int k8 = g / 1536, r = g % 1536, c = r >> 2, j = r & 3;
    const float* b = WIH2 + c*128 + k8*8 + 2*j;
    WIH2t[g] = pkh(b[0], b[1]);
  }
  for (int g = gid0; g < 16384; g += stride){
    int k4 = g >> 9, r = g & 511, c = r >> 2, j = r & 3;
    QWt[g] = QW[c*128 + k4*4 + j];
  }
}

// ---------------------------------------------------------------- khg: K_hist pre-gather (coalesced)
__global__ void k_khg(const int* __restrict__ question,
                      const float* __restrict__ EQ,
                      float* __restrict__ KHG)
{
  int o = blockIdx.x*256 + threadIdx.x;
  if (o < B_*S_*D_){
    int row = o >> 7;
    KHG[o] = EQ[question[row]*128 + (o & 127)];
  }
}

// ---------------------------------------------------------------- K1: hop aggregation (f16 dot2, coalesced Wt)
template<int ROWS>
__device__ __forceinline__ void agg_stage_h(const u16* __restrict__ tmph,
    const u32* __restrict__ Wt, const float* __restrict__ bg,
    u16* __restrict__ outh, int c)
{
  float bias = bg[c];
  float acc[ROWS];
  #pragma unroll
  for (int r = 0; r < ROWS; r++) acc[r] = bias;
  const uint4* wp = (const uint4*)Wt;
  if constexpr (ROWS <= 4){
    float acc2[ROWS];
    #pragma unroll
    for (int r = 0; r < ROWS; r++) acc2[r] = 0.f;
    #pragma unroll 4
    for (int g = 0; g < 16; g++){
      uint4 wv = wp[g*128 + c];
      #pragma unroll
      for (int r = 0; r < ROWS; r++){
        uint4 hv = *(const uint4*)(tmph + r*128 + g*8);
        acc[r]  = dot2f(wv.x, hv.x, acc[r]);
        acc2[r] = dot2f(wv.y, hv.y, acc2[r]);
        acc[r]  = dot2f(wv.z, hv.z, acc[r]);
        acc2[r] = dot2f(wv.w, hv.w, acc2[r]);
      }
    }
    #pragma unroll
    for (int r = 0; r < ROWS; r++)
      outh[r*128 + c] = f2h(fast_tanh(acc[r] + acc2[r]));
  } else {
    #pragma unroll 4
    for (int g = 0; g < 16; g++){
      uint4 wv = wp[g*128 + c];
      #pragma unroll
      for (int r = 0; r < ROWS; r++){
        uint4 hv = *(const uint4*)(tmph + r*128 + g*8);
        acc[r] = dot2f(wv.x, hv.x, acc[r]);
        acc[r] = dot2f(wv.y, hv.y, acc[r]);
        acc[r] = dot2f(wv.z, hv.z, acc[r]);
        acc[r] = dot2f(wv.w, hv.w, acc[r]);
      }
    }
    #pragma unroll
    for (int r = 0; r < ROWS; r++)
      outh[r*128 + c] = f2h(fast_tanh(acc[r]));
  }
}

__launch_bounds__(256, 4)
__global__ void k_agg(const int* __restrict__ question,
                      const int* __restrict__ q_neighbors,
                      const int* __restrict__ s_neighbors,
                      const float* __restrict__ EQ,
                      const float* __restrict__ EC,
                      const u32* __restrict__ AWt,
                      const float* __restrict__ AB,
                      const u32* __restrict__ ALWt,
                      const float* __restrict__ ALB,
                      const void* __restrict__ maskp,
                      const int* __restrict__ flags,
                      float* __restrict__ EQREC)
{
  __shared__ __align__(16) u16 e0h[2][128];
  __shared__ __align__(16) u16 e1h[2][512];
  __shared__ __align__(16) u16 e2h[2][2048];
  __shared__ __align__(16) u16 tmph[2][2048];
  __shared__ int nn1[2][4]; __shared__ int nn2[2][16]; __shared__ int nn3[2][64];
  const int tid  = threadIdx.x;
  const int c    = tid & 127;
  const int half = tid >> 7;
  const int bs   = blockIdx.x*2 + half;
  const int n0   = question[bs];
  u16* tp = tmph[half];

  if (c < 4) nn1[half][c] = q_neighbors[n0*4 + c];
  __syncthreads();
  if (c < 16) nn2[half][c] = s_neighbors[nn1[half][c>>2]*4 + (c&3)];
  __syncthreads();
  if (c < 64) nn3[half][c] = q_neighbors[nn2[half][c>>2]*4 + (c&3)];
  e0h[half][c] = f2h(EQ[n0*128 + c]);
  #pragma unroll
  for (int r = 0; r < 4; r++)  e1h[half][r*128 + c] = f2h(EC[nn1[half][r]*128 + c]);
  #pragma unroll 4
  for (int r = 0; r < 16; r++) e2h[half][r*128 + c] = f2h(EQ[nn2[half][r]*128 + c]);
  __syncthreads();

  auto fill_e0 = [&](){
    float v = 0.25f*(h2f(e1h[half][c]) + h2f(e1h[half][128+c])
                   + h2f(e1h[half][256+c]) + h2f(e1h[half][384+c]))
            + h2f(e0h[half][c]);
    tp[c] = f2h(v);
  };
  auto fill_e1 = [&](){
    #pragma unroll
    for (int r = 0; r < 4; r++){
      float v = 0.25f*(h2f(e2h[half][(4*r)*128+c])   + h2f(e2h[half][(4*r+1)*128+c])
                     + h2f(e2h[half][(4*r+2)*128+c]) + h2f(e2h[half][(4*r+3)*128+c]))
              + h2f(e1h[half][r*128 + c]);
      tp[r*128 + c] = f2h(v);
    }
  };

  fill_e0(); __syncthreads();
  agg_stage_h<1>(tp, AWt, AB, e0h[half], c); __syncthreads();
  fill_e1(); __syncthreads();
  agg_stage_h<4>(tp, AWt + 8192, AB + 128, e1h[half], c); __syncthreads();
  #pragma unroll 2
  for (int r = 0; r < 16; r++){
    float m = 0.25f*( EC[nn3[half][4*r]*128+c]   + EC[nn3[half][4*r+1]*128+c]
                    + EC[nn3[half][4*r+2]*128+c] + EC[nn3[half][4*r+3]*128+c] );
    tp[r*128 + c] = f2h(m + h2f(e2h[half][r*128 + c]));
  }
  __syncthreads();
  agg_stage_h<16>(tp, AWt + 16384, AB + 256, e2h[half], c); __syncthreads();
  fill_e0(); __syncthreads();
  agg_stage_h<1>(tp, AWt, AB, e0h[half], c); __syncthreads();
  fill_e1(); __syncthreads();
  agg_stage_h<4>(tp, AWt + 8192, AB + 128, e1h[half], c); __syncthreads();
  fill_e0(); __syncthreads();
  agg_stage_h<1>(tp, AWt, AB, e0h[half], c); __syncthreads();
  agg_stage_h<1>(e0h[half], ALWt, ALB, tp, c); __syncthreads();
  const int msk = readBool(maskp, bs, flags[1]);
  EQREC[bs*128 + c] = msk ? h2f(tp[c]) : EQ[n0*128 + c];
}

// ---------------------------------------------------------------- K2: gi1 precompute (K=256, f16 dot2, coalesced)
__launch_bounds__(384, 1)
__global__ void k_gi1(const float* __restrict__ EQREC,
                      const int* __restrict__ response,
                      const float* __restrict__ ECOR,
                      const u32* __restrict__ WIH1t,
                      const float* __restrict__ BIH1,
                      float* __restrict__ GI1)
{
  const int t  = blockIdx.x;
  const int bg = blockIdx.y;
  const int tid = threadIdx.x;
  __shared__ __align__(16) u16 X[8][256];
  for (int o = tid; o < 2048; o += 384){
    int bb = o >> 8, k = o & 255;
    int b = bg*8 + bb;
    float v = (k < 128) ? EQREC[(b*S_ + t)*128 + k]
                        : ECOR[response[b*S_ + t]*128 + (k - 128)];
    X[bb][k] = f2h(v);
  }
  __syncthreads();
  float bias = BIH1[tid];
  float acc[8];
  #pragma unroll
  for (int i = 0; i < 8; i++) acc[i] = bias;
  const uint4* wp = (const uint4*)WIH1t;
  #pragma unroll 4
  for (int g = 0; g < 32; g++){
    uint4 wv = wp[g*384 + tid];
    #pragma unroll
    for (int bb = 0; bb < 8; bb++){
      uint4 hv = *(const uint4*)(&X[bb][g*8]);
      acc[bb] = dot2f(wv.x, hv.x, acc[bb]);
      acc[bb] = dot2f(wv.y, hv.y, acc[bb]);
      acc[bb] = dot2f(wv.z, hv.z, acc[bb]);
      acc[bb] = dot2f(wv.w, hv.w, acc[bb]);
    }
  }
  #pragma unroll
  for (int bb = 0; bb < 8; bb++)
    GI1[(t*32 + bg*8 + bb)*384 + tid] = acc[bb];
}

// ---------------------------------------------------------------- K3: scores + top-10 (LDS-tiled, 2 passes)
#define NA_ 126
__global__ void k_topk(const float* __restrict__ KHG,
                       int* __restrict__ IDX)
{
  const int blk = blockIdx.x;
  const int t = blk >> 5, b = blk & 31;
  const int tid = threadIdx.x;               // 64
  __shared__ __align__(16) float tile[NA_*128];   // 64512 B
  __shared__ __align__(16) float qn[128];
  const float* KB_ = KHG + (size_t)b*S_*128;
  for (int o = tid; o < 128; o += 64) qn[o] = KB_[(t+1)*128 + o];
  const int nA = (t < NA_) ? t : NA_;
  {
    float4* td = (float4*)tile;
    const float4* sp = (const float4*)KB_;
    for (int o4 = tid; o4 < nA*32; o4 += 64) td[o4] = sp[o4];
  }
  __syncthreads();
  float val[4]; int sv[4];
  #pragma unroll
  for (int i = 0; i < 4; i++){
    int s = tid + 64*i;
    sv[i] = s;
    float v = -3.0e38f;                      // sentinel (s >= 200)
    if (s < S_){
      if (s >= t) v = NEGV;
      else if (s < nA) v = dot128f(tile + s*128, qn);
    }
    val[i] = v;
  }
  if (t > NA_){                              // pass B: rows [NA_, t)
    __syncthreads();
    int nB = t - NA_;
    float4* td = (float4*)tile;
    const float4* sp = (const float4*)(KB_ + NA_*128);
    for (int o4 = tid; o4 < nB*32; o4 += 64) td[o4] = sp[o4];
    __syncthreads();
    #pragma unroll
    for (int i = 0; i < 4; i++){
      int s = tid + 64*i;
      if (s >= NA_ && s < t) val[i] = dot128f(tile + (s-NA_)*128, qn);
    }
  }
  for (int r = 0; r < 10; r++){
    float bv = -3.0e38f; int bi = 0x3fffffff;
    #pragma unroll
    for (int i = 0; i < 4; i++){
      if (val[i] > bv || (val[i] == bv && sv[i] < bi)){ bv = val[i]; bi = sv[i]; }
    }
    for (int off = 32; off; off >>= 1){
      float ov = __shfl_down(bv, off);
      int   oi = __shfl_down(bi, off);
      if (ov > bv || (ov == bv && oi < bi)){ bv = ov; bi = oi; }
    }
    int win = __shfl(bi, 0);
    if (tid == 0) IDX[blk*10 + r] = win;
    #pragma unroll
    for (int i = 0; i < 4; i++) if (sv[i] == win) val[i] = -3.0e38f;
  }
}

// ---------------------------------------------------------------- K4: fused chain pipeline
// 96 blocks: role 0 = chain1 (producer), role 1 = gi2 worker, role 2 = chain2.
// All co-resident (96 < 256 CUs); producers never wait -> no deadlock.
// Flags at 4-step group granularity; release/acquire with agent scope.
__launch_bounds__(384, 1)
__global__ void k_chains(const float* __restrict__ GI1,
                         const u16* __restrict__ WHH1h,
                         const float* __restrict__ BHH1,
                         const float* __restrict__ H1I,
                         float* __restrict__ H1ALL,
                         const u32* __restrict__ WIH2t,
                         const float* __restrict__ BIH2,
                         float* __restrict__ GI2,
                         const u16* __restrict__ WHH2h,
                         const float* __restrict__ BHH2,
                         const float* __restrict__ H2I,
                         float* __restrict__ G2,
                         int* __restrict__ FLAG1,
                         int* __restrict__ FLAG2)
{
  const int role = blockIdx.x >> 5;
  const int b   = blockIdx.x & 31;
  const int tid = threadIdx.x;

  if (role == 1){
    // -------- gi2 worker: GI2[t] = bih2 + Wih2 @ H1ALL[t]
    __shared__ __align__(16) u16 Xh[4][128];
    uint4 W[16];
    {
      const uint4* wp = (const uint4*)WIH2t;
      #pragma unroll
      for (int g = 0; g < 16; g++) W[g] = wp[g*384 + tid];   // coalesced, once
    }
    const float bias = BIH2[tid];
    for (int g = 0; g < NG_; g++){
      wait_flag(&FLAG1[b*64 + g], tid);
      const int t0 = g*4;
      for (int o = tid; o < 512; o += 384){
        int ph = o >> 7, c = o & 127, t = t0 + ph;
        if (t < T_) Xh[ph][c] = f2h(H1ALL[(t*32 + b)*128 + c]);
      }
      __syncthreads();
      #pragma unroll
      for (int ph = 0; ph < 4; ph++){
        int t = t0 + ph;
        if (t >= T_) break;
        float a = bias, a2 = 0.f;
        #pragma unroll 4
        for (int gg = 0; gg < 16; gg++){
          uint4 wv = W[gg];
          uint4 hv = *(const uint4*)(&Xh[ph][gg*8]);
          a  = dot2f(wv.x, hv.x, a);
          a2 = dot2f(wv.y, hv.y, a2);
          a  = dot2f(wv.z, hv.z, a);
          a2 = dot2f(wv.w, hv.w, a2);
        }
        GI2[(t*32 + b)*384 + tid] = a + a2;
      }
      set_flag(&FLAG2[b*64 + g], tid);
    }
    return;
  }

  // -------- chain roles share structure
  const int is1 = (role == 0);
  __shared__ __align__(16) float h[128];
  __shared__ __align__(16) u16 hh[128];
  __shared__ float gh[384];
  const float* GIx  = is1 ? GI1 : GI2;
  const u16*   Wh   = is1 ? WHH1h : WHH2h;
  const float* Bx   = is1 ? BHH1 : BHH2;
  const float* HIx  = is1 ? H1I : H2I;
  float*       OUTx = is1 ? H1ALL : G2;
  if (tid < 128){ float v = HIx[b*128 + tid]; h[tid] = v; hh[tid] = f2h(v); }
  const float bias = Bx[tid];
  u32 W[64];
  {
    const uint4* wp = (const uint4*)(Wh + tid*128);
    #pragma unroll
    for (int i = 0; i < 16; i++){
      uint4 v = wp[i];
      W[4*i] = v.x; W[4*i+1] = v.y; W[4*i+2] = v.z; W[4*i+3] = v.w;
    }
  }
  float cur[4][3] = {}, nxt[4][3] = {}, st[4] = {};
  if (!is1) wait_flag(&FLAG2[b*64 + 0], tid);
  if (tid < 128){
    #pragma unroll
    for (int i = 0; i < 4; i++){
      const float* gp = GIx + (i*32 + b)*384;
      cur[i][0] = gp[tid]; cur[i][1] = gp[128+tid]; cur[i][2] = gp[256+tid];
    }
  }
  __syncthreads();
  for (int t0 = 0; t0 < T_; t0 += 4){
    const int gn = (t0 >> 2) + 1;
    if (gn < NG_){
      if (!is1) wait_flag(&FLAG2[b*64 + gn], tid);
      if (tid < 128){
        #pragma unroll
        for (int i = 0; i < 4; i++){
          int tt = t0 + 4 + i;
          if (tt < T_){
            const float* gp = GIx + (tt*32 + b)*384;
            nxt[i][0] = gp[tid]; nxt[i][1] = gp[128+tid]; nxt[i][2] = gp[256+tid];
          }
        }
      }
    }
    #pragma unroll
    for (int ph = 0; ph < 4; ph++){
      const int t = t0 + ph;
      if (t >= T_) break;
      float a = bias, ab = 0.f;
      #pragma unroll
      for (int i = 0; i < 16; i++){
        uint4 hv = *(const uint4*)(hh + i*8);
        a  = dot2f(W[4*i],   hv.x, a);
        ab = dot2f(W[4*i+1], hv.y, ab);
        a  = dot2f(W[4*i+2], hv.z, a);
        ab = dot2f(W[4*i+3], hv.w, ab);
      }
      gh[tid] = a + ab;
      __syncthreads();
      if (tid < 128){
        float r = fast_sigmoid(cur[ph][0] + gh[tid]);
        float z = fast_sigmoid(cur[ph][1] + gh[128+tid]);
        float n = fast_tanh(cur[ph][2] + r*gh[256+tid]);
        float g = (1.f - z)*n + z*h[tid];
        st[ph] = g;
        if (is1 || t > 0){ h[tid] = g; hh[tid] = f2h(g); }
      }
      __syncthreads();
    }
    if (tid < 128){
      #pragma unroll
      for (int ph = 0; ph < 4; ph++){
        int t = t0 + ph;
        if (t < T_) OUTx[(t*32 + b)*128 + tid] = st[ph];
      }
      #pragma unroll
      for (int i = 0; i < 4; i++){
        cur[i][0] = nxt[i][0]; cur[i][1] = nxt[i][1]; cur[i][2] = nxt[i][2];
      }
    }
    if (is1) set_flag(&FLAG1[b*64 + (t0 >> 2)], tid);
  }
}

// ---------------------------------------------------------------- K5: Kp·w_k for all G2 rows (coalesced QWt)
__launch_bounds__(128, 4)
__global__ void k_kp(const float* __restrict__ G2,
                     const float* __restrict__ QWt, const float* __restrict__ QB,
                     const float* __restrict__ MW,
                     float* __restrict__ KPWG)
{
  __shared__ __align__(16) float X[8][128];
  __shared__ float red[8][2];
  const int tid = threadIdx.x;
  const int base = blockIdx.x * 8;
  for (int o = tid; o < 1024; o += 128){
    int r = o >> 7, c = o & 127;
    X[r][c] = G2[(base + r)*128 + c];
  }
  __syncthreads();
  float acc[8];
  float bias = QB[tid];
  #pragma unroll
  for (int r = 0; r < 8; r++) acc[r] = bias;
  const float4* wp = (const float4*)QWt;
  #pragma unroll 4
  for (int g = 0; g < 32; g++){
    float4 wv = wp[g*128 + tid];
    int kk = 4*g;
    #pragma unroll
    for (int r = 0; r < 8; r++){
      float4 t4 = *(const float4*)(&X[r][kk]);
      acc[r] = fmaf(t4.x, wv.x, acc[r]);
      acc[r] = fmaf(t4.y, wv.y, acc[r]);
      acc[r] = fmaf(t4.z, wv.z, acc[r]);
      acc[r] = fmaf(t4.w, wv.w, acc[r]);
    }
  }
  const float wk = MW[128 + tid];
  const int lane = tid & 63, wv_ = tid >> 6;
  #pragma unroll
  for (int r = 0; r < 8; r++){
    float pv = fast_tanh(acc[r]) * wk;
    for (int off = 32; off; off >>= 1) pv += __shfl_down(pv, off);
    if (lane == 0) red[r][wv_] = pv;
  }
  __syncthreads();
  if (tid < 8) KPWG[base + tid] = red[tid][0] + red[tid][1];
}

// ---------------------------------------------------------------- K6: predict + output
__global__ void k_pred(const int* __restrict__ question,
                       const int* __restrict__ qci, const void* __restrict__ qcm,
                       const int* __restrict__ flags,
                       const float* __restrict__ EQ, const float* __restrict__ EC,
                       const float* __restrict__ QB, const float* __restrict__ MW,
                       const float* __restrict__ G2,
                       const int* __restrict__ IDX,
                       const float* __restrict__ KPWG,
                       void* __restrict__ outp)
{
  const int blk = blockIdx.x;
  const int t = blk >> 5, b = blk & 31;
  const int tid = threadIdx.x;               // 64
  __shared__ float hist[11][132];
  __shared__ float qcs[128];
  __shared__ float og[11];
  __shared__ float kpw[11];
  __shared__ int   idxs[10];
  __shared__ float kpw0s;
  const int qid = question[b*S_ + t + 1];
  const int bflag = flags[1];
  if (tid < 10) idxs[tid] = IDX[blk*10 + tid];
  __syncthreads();
  for (int o = tid; o < 11*128; o += 64){
    int k = o >> 7, c = o & 127;
    float v;
    if (k == 0) v = G2[blk*128 + c];
    else { int s = idxs[k-1]; v = (s == 0) ? 0.f : G2[(s*32 + b)*128 + c]; }
    hist[k][c] = v;
  }
  #pragma unroll
  for (int o = tid; o < 128; o += 64){
    float v = EQ[qid*128 + o];
    #pragma unroll
    for (int q = 0; q < 4; q++){
      if (readBool(qcm, qid*4 + q, bflag))
        v += EC[qci[qid*4 + q]*128 + o];
    }
    qcs[o] = v;
  }
  {
    float pv = fast_tanh(QB[tid])      * MW[128 + tid]
             + fast_tanh(QB[tid + 64]) * MW[128 + tid + 64];
    for (int off = 32; off; off >>= 1) pv += __shfl_down(pv, off);
    if (tid == 0) kpw0s = pv;
  }
  __syncthreads();
  if (tid < 11){
    float acc = 0.f;
    for (int c = 0; c < 128; c++) acc = fmaf(qcs[c], hist[tid][c], acc);
    og[tid] = acc;
    float v;
    if (tid == 0) v = KPWG[blk];
    else { int s = idxs[tid-1]; v = (s == 0) ? kpw0s : KPWG[s*32 + b]; }
    kpw[tid] = v;
  }
  __syncthreads();
  if (tid == 0){
    float tv[11];
    #pragma unroll
    for (int k = 0; k < 11; k++){
      int valid = (k == 0) || (idxs[k-1] < t);
      tv[k] = valid ? kpw[k] : NEGV;
    }
    float m = tv[0];
    #pragma unroll
    for (int k = 1; k < 11; k++) m = fmaxf(m, tv[k]);
    float den = 0.f, num = 0.f;
    #pragma unroll
    for (int k = 0; k < 11; k++){
      float e = __expf(tv[k] - m);
      den += e;
      num = fmaf(e, og[k], num);
    }
    float p = num / den;
    int col = (t == 0) ? 0 : (t + 1);
    if (flags[0]){
      ((float*)outp)[b*S_ + col] = p;
      if (t == 0) ((float*)outp)[b*S_ + 1] = 0.f;
    } else {
      ((u16*)outp)[b*S_ + col] = f2bf(p);
      if (t == 0) ((u16*)outp)[b*S_ + 1] = (u16)0;
    }
  }
}

// ---------------------------------------------------------------- launcher
extern "C" void kernel_launch(void* const* d_in, const int* in_sizes, int n_in,
                              void* d_out, int out_size, void* d_ws, size_t ws_size,
                              hipStream_t stream)
{
  (void)in_sizes; (void)n_in; (void)out_size; (void)ws_size;
  const int* question      = (const int*)d_in[0];
  const int* response      = (const int*)d_in[1];
  const void* maskp        = d_in[2];
  const int* q_neighbors   = (const int*)d_in[3];
  const int* s_neighbors   = (const int*)d_in[4];
  const int* q_concept_idx = (const int*)d_in[5];
  const void* q_concept_mask = d_in[6];

  static const int CN[NCVT] = {2560000,256000,256,98304,49152,384,384,49152,49152,
                               384,384,49152,384,16384,128,16384,128,16384,128,
                               256,1,4096,4096};
  CvtArgs ca;
  int off = 0;
  for (int i = 0; i < NCVT; i++){
    ca.s[i] = d_in[7 + i];
    ca.nreal[i] = CN[i];
    ca.off[i] = off;
    off += (CN[i] + 3) & ~3;
  }
  ca.off[NCVT] = off;
  const int total = off;

  char* ws = (char*)d_ws;
  size_t wo = 0;
  auto alloc = [&](size_t bytes) -> void* {
    void* p = ws + wo;
    wo = (wo + bytes + 255) & ~(size_t)255;
    return p;
  };
  int*   flags = (int*)  alloc(16);
  float* CVT   = (float*)alloc((size_t)total * 4);
  float* EQREC = (float*)alloc((size_t)B_*S_*D_*4);
  float* GI1   = (float*)alloc((size_t)T_*B_*384*4);
  float* GI2A  = (float*)alloc((size_t)T_*B_*384*4);
  float* H1ALL = (float*)alloc((size_t)T_*B_*D_*4);
  float* G2    = (float*)alloc((size_t)T_*B_*D_*4);
  int*   IDX   = (int*)  alloc((size_t)T_*B_*10*4);
  float* KPWG  = (float*)alloc((size_t)T_*B_*4);
  float* KHG   = (float*)alloc((size_t)B_*S_*D_*4);
  int*   PFLAG = (int*)  alloc(2*32*64*4);        // FLAG1 | FLAG2
  u16*   WHH1h = (u16*)  alloc(49152*2);
  u16*   WHH2h = (u16*)  alloc(49152*2);
  u32*   AWt   = (u32*)  alloc(24576*4);
  u32*   ALWt  = (u32*)  alloc(8192*4);
  u32*   WIH1t = (u32*)  alloc(49152*4);
  u32*   WIH2t = (u32*)  alloc(24576*4);
  float* QWt   = (float*)alloc(16384*4);
  int*   FLAG1 = PFLAG;
  int*   FLAG2 = PFLAG + 32*64;

  const float* EQ   = CVT + ca.off[0];
  const float* EC   = CVT + ca.off[1];
  const float* ECOR = CVT + ca.off[2];
  const float* WIH1 = CVT + ca.off[3];
  const float* WHH1 = CVT + ca.off[4];
  const float* BIH1 = CVT + ca.off[5];
  const float* BHH1 = CVT + ca.off[6];
  const float* WIH2 = CVT + ca.off[7];
  const float* WHH2 = CVT + ca.off[8];
  const float* BIH2 = CVT + ca.off[9];
  const float* BHH2 = CVT + ca.off[10];
  const float* AW   = CVT + ca.off[11];
  const float* AB   = CVT + ca.off[12];
  const float* ALW  = CVT + ca.off[13];
  const float* ALB  = CVT + ca.off[14];
  const float* QW   = CVT + ca.off[15];
  const float* QB   = CVT + ca.off[16];
  const float* MW   = CVT + ca.off[19];
  const float* H1I  = CVT + ca.off[21];
  const float* H2I  = CVT + ca.off[22];

  hipMemsetAsync(PFLAG, 0, 2*32*64*4, stream);
  k_sniff2<<<1, 256, 0, stream>>>((const u16*)d_in[7], (const unsigned char*)maskp, flags);
  k_cvt<<<(total + 255)/256, 256, 0, stream>>>(ca, flags, CVT);
  k_prep<<<192, 256, 0, stream>>>(WHH1, WHH2, AW, ALW, WIH1, WIH2, QW,
                                  WHH1h, WHH2h, AWt, ALWt, WIH1t, WIH2t, QWt);
  k_khg<<<(B_*S_*D_ + 255)/256, 256, 0, stream>>>(question, EQ, KHG);
  k_agg<<<B_*S_/2, 256, 0, stream>>>(question, q_neighbors, s_neighbors, EQ, EC,
                                     AWt, AB, ALWt, ALB, maskp, flags, EQREC);
  k_gi1<<<dim3(T_, 4), 384, 0, stream>>>(EQREC, response, ECOR, WIH1t, BIH1, GI1);
  k_topk<<<T_*B_, 64, 0, stream>>>(KHG, IDX);
  k_chains<<<96, 384, 0, stream>>>(GI1, WHH1h, BHH1, H1I, H1ALL,
                                   WIH2t, BIH2, GI2A,
                                   WHH2h, BHH2, H2I, G2,
                                   FLAG1, FLAG2);
  k_kp<<<T_*B_/8, 128, 0, stream>>>(G2, QWt, QB, MW, KPWG);
  k_pred<<<T_*B_, 64, 0, stream>>>(question, q_concept_idx, q_concept_mask, flags,
                                   EQ, EC, QB, MW, G2, IDX, KPWG, d_out);
}

// Round 14
// 783.957 us; speedup vs baseline: 2.1731x; 2.1731x over previous
//
#include <hip/hip_runtime.h>
#include <math.h>

typedef unsigned short u16;
typedef unsigned int   u32;
typedef __attribute__((ext_vector_type(2))) _Float16 half2_t;

#define B_   32
#define S_   200
#define D_   128
#define T_   199
#define NEGV (-1e30f)

__device__ __forceinline__ float bf2f(u16 u){
  union { u32 i; float f; } v; v.i = ((u32)u) << 16; return v.f;
}
__device__ __forceinline__ u16 f2bf(float f){
  union { float f; u32 i; } v; v.f = f;
  u32 x = v.i;
  return (u16)((x + 0x7fffu + ((x >> 16) & 1u)) >> 16);   // RNE
}
__device__ __forceinline__ u16 f2h(float x){
  union { _Float16 h; u16 u; } v; v.h = (_Float16)x; return v.u;
}
__device__ __forceinline__ float h2f(u16 u){
  union { u16 u; _Float16 h; } v; v.u = u; return (float)v.h;
}
__device__ __forceinline__ u32 pkh(float lo, float hi){
  return ((u32)f2h(hi) << 16) | f2h(lo);
}
__device__ __forceinline__ float dot2f(u32 w, u32 h, float acc){
#if __has_builtin(__builtin_amdgcn_fdot2)
  union { u32 u; half2_t h2; } a, b;
  a.u = w; b.u = h;
  return __builtin_amdgcn_fdot2(a.h2, b.h2, acc, false);
#else
  union { u32 u; _Float16 f[2]; } a, b;
  a.u = w; b.u = h;
  acc = fmaf((float)a.f[0], (float)b.f[0], acc);
  return fmaf((float)a.f[1], (float)b.f[1], acc);
#endif
}
__device__ __forceinline__ float fast_sigmoid(float x){ return 1.f/(1.f+__expf(-x)); }
__device__ __forceinline__ float fast_tanh(float x){
  float e = __expf(2.f*x);
  return 1.f - 2.f/(e + 1.f);
}

// bool storage modes: 0=int32, 1=u8, 2=bf16, 3=f32
__device__ __forceinline__ int readBool(const void* p, int i, int m){
  if (m == 0) return ((const int*)p)[i] != 0;
  if (m == 1) return ((const unsigned char*)p)[i] != 0;
  if (m == 2) return ((const u16*)p)[i] != 0;
  return ((const u32*)p)[i] != 0;
}

__device__ __forceinline__ float dot128f(const float* __restrict__ w,
                                         const float* __restrict__ x){
  float acc = 0.f;
  const float4* wp = (const float4*)w;
  #pragma unroll 8
  for (int i = 0; i < 32; i++){
    float4 v = wp[i]; int k = 4*i;
    acc = fmaf(v.x, x[k],   acc);
    acc = fmaf(v.y, x[k+1], acc);
    acc = fmaf(v.z, x[k+2], acc);
    acc = fmaf(v.w, x[k+3], acc);
  }
  return acc;
}

// ---------------------------------------------------------------- sniffer
__global__ void k_sniff2(const u16* __restrict__ embq_raw,
                         const unsigned char* __restrict__ mask_raw,
                         int* __restrict__ flags){
  __shared__ int bad, gt1, m4, b0;
  const int tid = threadIdx.x;
  if (tid == 0){ bad = 0; gt1 = 0; m4 = 0; b0 = 0; }
  __syncthreads();
  for (int i = tid; i < 512; i += 256){
    u16 u = embq_raw[i];
    if (u){ int e = (u >> 7) & 0xFF; if (e < 0x58 || e > 0x7F) atomicAdd(&bad, 1); }
  }
  for (int i = tid; i < 1024; i += 256){
    unsigned char c = mask_raw[i];
    if (c > 1) atomicAdd(&gt1, 1);
    if (c && (i & 3)) atomicAdd(&m4, 1);
    if (c && !(i & 3)) atomicAdd(&b0, 1);
  }
  __syncthreads();
  if (tid == 0){
    flags[0] = (bad >= 16) ? 1 : 0;
    flags[1] = gt1 ? (b0 ? 2 : 3) : (m4 ? 1 : 0);
  }
}

// ---------------------------------------------------------------- convert floats -> f32
#define NCVT 23
struct CvtArgs { const void* s[NCVT]; int off[NCVT+1]; int nreal[NCVT]; };

__global__ void k_cvt(CvtArgs a, const int* __restrict__ flags, float* __restrict__ dst){
  __shared__ int f;
  if (threadIdx.x == 0) f = flags[0];
  __syncthreads();
  int gid = blockIdx.x * 256 + threadIdx.x;
  if (gid >= a.off[NCVT]) return;
  int ai = 0;
  for (int i = 1; i < NCVT; i++) if (gid >= a.off[i]) ai = i;
  int i = gid - a.off[ai];
  float v = 0.f;
  if (i < a.nreal[ai])
    v = f ? ((const float*)a.s[ai])[i] : bf2f(((const u16*)a.s[ai])[i]);
  dst[gid] = v;
}

// ---------------------------------------------------------------- prep (transposed/coalesced weights)
__global__ void k_prep(const float* __restrict__ WHH1, const float* __restrict__ WHH2,
                       const float* __restrict__ AW,   const float* __restrict__ ALW,
                       const float* __restrict__ WIH1, const float* __restrict__ WIH2,
                       const float* __restrict__ QW,
                       u16* __restrict__ WHH1h, u16* __restrict__ WHH2h,
                       u32* __restrict__ AWt,   u32* __restrict__ ALWt,
                       u32* __restrict__ WIH1t, u32* __restrict__ WIH2t,
                       float* __restrict__ QWt)
{
  const int gid0 = blockIdx.x*256 + threadIdx.x;
  const int stride = gridDim.x*256;
  for (int g = gid0; g < 49152; g += stride){
    WHH1h[g] = f2h(WHH1[g]);
    WHH2h[g] = f2h(WHH2[g]);
  }
  for (int g = gid0; g < 24576; g += stride){
    int s = g >> 13, w = g & 8191;
    int k8 = w >> 9, r = w & 511, c = r >> 2, j = r & 3;
    const float* b = AW + s*16384 + c*128 + k8*8 + 2*j;
    AWt[g] = pkh(b[0], b[1]);
  }
  for (int g = gid0; g < 8192; g += stride){
    int k8 = g >> 9, r = g & 511, c = r >> 2, j = r & 3;
    const float* b = ALW + c*128 + k8*8 + 2*j;
    ALWt[g] = pkh(b[0], b[1]);
  }
  for (int g = gid0; g < 49152; g += stride){
    int k8 = g / 1536, r = g % 1536, c = r >> 2, j = r & 3;
    const float* b = WIH1 + c*256 + k8*8 + 2*j;
    WIH1t[g] = pkh(b[0], b[1]);
  }
  for (int g = gid0; g < 24576; g += stride){
    int k8 = g / 1536, r = g % 1536, c = r >> 2, j = r & 3;
    const float* b = WIH2 + c*128 + k8*8 + 2*j;
    WIH2t[g] = pkh(b[0], b[1]);
  }
  for (int g = gid0; g < 16384; g += stride){
    int k4 = g >> 9, r = g & 511, c = r >> 2, j = r & 3;
    QWt[g] = QW[c*128 + k4*4 + j];
  }
}

// ---------------------------------------------------------------- khg: K_hist pre-gather (coalesced)
__global__ void k_khg(const int* __restrict__ question,
                      const float* __restrict__ EQ,
                      float* __restrict__ KHG)
{
  int o = blockIdx.x*256 + threadIdx.x;
  if (o < B_*S_*D_){
    int row = o >> 7;
    KHG[o] = EQ[question[row]*128 + (o & 127)];
  }
}

// ---------------------------------------------------------------- K1: hop aggregation (f16 dot2, coalesced Wt)
template<int ROWS>
__device__ __forceinline__ void agg_stage_h(const u16* __restrict__ tmph,
    const u32* __restrict__ Wt, const float* __restrict__ bg,
    u16* __restrict__ outh, int c)
{
  float bias = bg[c];
  float acc[ROWS];
  #pragma unroll
  for (int r = 0; r < ROWS; r++) acc[r] = bias;
  const uint4* wp = (const uint4*)Wt;
  if constexpr (ROWS <= 4){
    float acc2[ROWS];
    #pragma unroll
    for (int r = 0; r < ROWS; r++) acc2[r] = 0.f;
    #pragma unroll 4
    for (int g = 0; g < 16; g++){
      uint4 wv = wp[g*128 + c];
      #pragma unroll
      for (int r = 0; r < ROWS; r++){
        uint4 hv = *(const uint4*)(tmph + r*128 + g*8);
        acc[r]  = dot2f(wv.x, hv.x, acc[r]);
        acc2[r] = dot2f(wv.y, hv.y, acc2[r]);
        acc[r]  = dot2f(wv.z, hv.z, acc[r]);
        acc2[r] = dot2f(wv.w, hv.w, acc2[r]);
      }
    }
    #pragma unroll
    for (int r = 0; r < ROWS; r++)
      outh[r*128 + c] = f2h(fast_tanh(acc[r] + acc2[r]));
  } else {
    #pragma unroll 4
    for (int g = 0; g < 16; g++){
      uint4 wv = wp[g*128 + c];
      #pragma unroll
      for (int r = 0; r < ROWS; r++){
        uint4 hv = *(const uint4*)(tmph + r*128 + g*8);
        acc[r] = dot2f(wv.x, hv.x, acc[r]);
        acc[r] = dot2f(wv.y, hv.y, acc[r]);
        acc[r] = dot2f(wv.z, hv.z, acc[r]);
        acc[r] = dot2f(wv.w, hv.w, acc[r]);
      }
    }
    #pragma unroll
    for (int r = 0; r < ROWS; r++)
      outh[r*128 + c] = f2h(fast_tanh(acc[r]));
  }
}

__launch_bounds__(256, 4)
__global__ void k_agg(const int* __restrict__ question,
                      const int* __restrict__ q_neighbors,
                      const int* __restrict__ s_neighbors,
                      const float* __restrict__ EQ,
                      const float* __restrict__ EC,
                      const u32* __restrict__ AWt,
                      const float* __restrict__ AB,
                      const u32* __restrict__ ALWt,
                      const float* __restrict__ ALB,
                      const void* __restrict__ maskp,
                      const int* __restrict__ flags,
                      float* __restrict__ EQREC)
{
  __shared__ __align__(16) u16 e0h[2][128];
  __shared__ __align__(16) u16 e1h[2][512];
  __shared__ __align__(16) u16 e2h[2][2048];
  __shared__ __align__(16) u16 tmph[2][2048];
  __shared__ int nn1[2][4]; __shared__ int nn2[2][16]; __shared__ int nn3[2][64];
  const int tid  = threadIdx.x;
  const int c    = tid & 127;
  const int half = tid >> 7;
  const int bs   = blockIdx.x*2 + half;
  const int n0   = question[bs];
  u16* tp = tmph[half];

  if (c < 4) nn1[half][c] = q_neighbors[n0*4 + c];
  __syncthreads();
  if (c < 16) nn2[half][c] = s_neighbors[nn1[half][c>>2]*4 + (c&3)];
  __syncthreads();
  if (c < 64) nn3[half][c] = q_neighbors[nn2[half][c>>2]*4 + (c&3)];
  e0h[half][c] = f2h(EQ[n0*128 + c]);
  #pragma unroll
  for (int r = 0; r < 4; r++)  e1h[half][r*128 + c] = f2h(EC[nn1[half][r]*128 + c]);
  #pragma unroll 4
  for (int r = 0; r < 16; r++) e2h[half][r*128 + c] = f2h(EQ[nn2[half][r]*128 + c]);
  __syncthreads();

  auto fill_e0 = [&](){
    float v = 0.25f*(h2f(e1h[half][c]) + h2f(e1h[half][128+c])
                   + h2f(e1h[half][256+c]) + h2f(e1h[half][384+c]))
            + h2f(e0h[half][c]);
    tp[c] = f2h(v);
  };
  auto fill_e1 = [&](){
    #pragma unroll
    for (int r = 0; r < 4; r++){
      float v = 0.25f*(h2f(e2h[half][(4*r)*128+c])   + h2f(e2h[half][(4*r+1)*128+c])
                     + h2f(e2h[half][(4*r+2)*128+c]) + h2f(e2h[half][(4*r+3)*128+c]))
              + h2f(e1h[half][r*128 + c]);
      tp[r*128 + c] = f2h(v);
    }
  };

  fill_e0(); __syncthreads();
  agg_stage_h<1>(tp, AWt, AB, e0h[half], c); __syncthreads();
  fill_e1(); __syncthreads();
  agg_stage_h<4>(tp, AWt + 8192, AB + 128, e1h[half], c); __syncthreads();
  #pragma unroll 2
  for (int r = 0; r < 16; r++){
    float m = 0.25f*( EC[nn3[half][4*r]*128+c]   + EC[nn3[half][4*r+1]*128+c]
                    + EC[nn3[half][4*r+2]*128+c] + EC[nn3[half][4*r+3]*128+c] );
    tp[r*128 + c] = f2h(m + h2f(e2h[half][r*128 + c]));
  }
  __syncthreads();
  agg_stage_h<16>(tp, AWt + 16384, AB + 256, e2h[half], c); __syncthreads();
  fill_e0(); __syncthreads();
  agg_stage_h<1>(tp, AWt, AB, e0h[half], c); __syncthreads();
  fill_e1(); __syncthreads();
  agg_stage_h<4>(tp, AWt + 8192, AB + 128, e1h[half], c); __syncthreads();
  fill_e0(); __syncthreads();
  agg_stage_h<1>(tp, AWt, AB, e0h[half], c); __syncthreads();
  agg_stage_h<1>(e0h[half], ALWt, ALB, tp, c); __syncthreads();
  const int msk = readBool(maskp, bs, flags[1]);
  EQREC[bs*128 + c] = msk ? h2f(tp[c]) : EQ[n0*128 + c];
}

// ---------------------------------------------------------------- K2: gi1 precompute (K=256, f16 dot2, coalesced)
__launch_bounds__(384, 1)
__global__ void k_gi1(const float* __restrict__ EQREC,
                      const int* __restrict__ response,
                      const float* __restrict__ ECOR,
                      const u32* __restrict__ WIH1t,
                      const float* __restrict__ BIH1,
                      float* __restrict__ GI1)
{
  const int t  = blockIdx.x;
  const int bg = blockIdx.y;
  const int tid = threadIdx.x;
  __shared__ __align__(16) u16 X[8][256];
  for (int o = tid; o < 2048; o += 384){
    int bb = o >> 8, k = o & 255;
    int b = bg*8 + bb;
    float v = (k < 128) ? EQREC[(b*S_ + t)*128 + k]
                        : ECOR[response[b*S_ + t]*128 + (k - 128)];
    X[bb][k] = f2h(v);
  }
  __syncthreads();
  float bias = BIH1[tid];
  float acc[8];
  #pragma unroll
  for (int i = 0; i < 8; i++) acc[i] = bias;
  const uint4* wp = (const uint4*)WIH1t;
  #pragma unroll 4
  for (int g = 0; g < 32; g++){
    uint4 wv = wp[g*384 + tid];
    #pragma unroll
    for (int bb = 0; bb < 8; bb++){
      uint4 hv = *(const uint4*)(&X[bb][g*8]);
      acc[bb] = dot2f(wv.x, hv.x, acc[bb]);
      acc[bb] = dot2f(wv.y, hv.y, acc[bb]);
      acc[bb] = dot2f(wv.z, hv.z, acc[bb]);
      acc[bb] = dot2f(wv.w, hv.w, acc[bb]);
    }
  }
  #pragma unroll
  for (int bb = 0; bb < 8; bb++)
    GI1[(t*32 + bg*8 + bb)*384 + tid] = acc[bb];
}

// ---------------------------------------------------------------- K2b: gi2 precompute (K=128, f16 dot2, coalesced)
__launch_bounds__(384, 1)
__global__ void k_gi2(const float* __restrict__ H1ALL,
                      const u32* __restrict__ WIH2t,
                      const float* __restrict__ BIH2,
                      float* __restrict__ GI2)
{
  const int t  = blockIdx.x;
  const int bg = blockIdx.y;
  const int tid = threadIdx.x;
  __shared__ __align__(16) u16 X[8][128];
  for (int o = tid; o < 1024; o += 384){
    int bb = o >> 7, k = o & 127;
    int b = bg*8 + bb;
    X[bb][k] = f2h(H1ALL[(t*32 + b)*128 + k]);
  }
  __syncthreads();
  float bias = BIH2[tid];
  float acc[8];
  #pragma unroll
  for (int i = 0; i < 8; i++) acc[i] = bias;
  const uint4* wp = (const uint4*)WIH2t;
  #pragma unroll 4
  for (int g = 0; g < 16; g++){
    uint4 wv = wp[g*384 + tid];
    #pragma unroll
    for (int bb = 0; bb < 8; bb++){
      uint4 hv = *(const uint4*)(&X[bb][g*8]);
      acc[bb] = dot2f(wv.x, hv.x, acc[bb]);
      acc[bb] = dot2f(wv.y, hv.y, acc[bb]);
      acc[bb] = dot2f(wv.z, hv.z, acc[bb]);
      acc[bb] = dot2f(wv.w, hv.w, acc[bb]);
    }
  }
  #pragma unroll
  for (int bb = 0; bb < 8; bb++)
    GI2[(t*32 + bg*8 + bb)*384 + tid] = acc[bb];
}

// ---------------------------------------------------------------- K3: scores + top-10 (LDS-tiled, 2 passes)
#define NA_ 126
__global__ void k_topk(const float* __restrict__ KHG,
                       int* __restrict__ IDX)
{
  const int blk = blockIdx.x;
  const int t = blk >> 5, b = blk & 31;
  const int tid = threadIdx.x;               // 64
  __shared__ __align__(16) float tile[NA_*128];   // 64512 B
  __shared__ __align__(16) float qn[128];
  const float* KB_ = KHG + (size_t)b*S_*128;
  for (int o = tid; o < 128; o += 64) qn[o] = KB_[(t+1)*128 + o];
  const int nA = (t < NA_) ? t : NA_;
  {
    float4* td = (float4*)tile;
    const float4* sp = (const float4*)KB_;
    for (int o4 = tid; o4 < nA*32; o4 += 64) td[o4] = sp[o4];
  }
  __syncthreads();
  float val[4]; int sv[4];
  #pragma unroll
  for (int i = 0; i < 4; i++){
    int s = tid + 64*i;
    sv[i] = s;
    float v = -3.0e38f;
    if (s < S_){
      if (s >= t) v = NEGV;
      else if (s < nA) v = dot128f(tile + s*128, qn);
    }
    val[i] = v;
  }
  if (t > NA_){
    __syncthreads();
    int nB = t - NA_;
    float4* td = (float4*)tile;
    const float4* sp = (const float4*)(KB_ + NA_*128);
    for (int o4 = tid; o4 < nB*32; o4 += 64) td[o4] = sp[o4];
    __syncthreads();
    #pragma unroll
    for (int i = 0; i < 4; i++){
      int s = tid + 64*i;
      if (s >= NA_ && s < t) val[i] = dot128f(tile + (s-NA_)*128, qn);
    }
  }
  for (int r = 0; r < 10; r++){
    float bv = -3.0e38f; int bi = 0x3fffffff;
    #pragma unroll
    for (int i = 0; i < 4; i++){
      if (val[i] > bv || (val[i] == bv && sv[i] < bi)){ bv = val[i]; bi = sv[i]; }
    }
    for (int off = 32; off; off >>= 1){
      float ov = __shfl_down(bv, off);
      int   oi = __shfl_down(bi, off);
      if (ov > bv || (ov == bv && oi < bi)){ bv = ov; bi = oi; }
    }
    int win = __shfl(bi, 0);
    if (tid == 0) IDX[blk*10 + r] = win;
    #pragma unroll
    for (int i = 0; i < 4; i++) if (sv[i] == win) val[i] = -3.0e38f;
  }
}

// ---------------------------------------------------------------- K4a: h1 chain (f16 dot2, batched groups of 4)
// r13 lesson: cross-block producer/consumer flags cost ~24 us/hop on MI355X
// (agent-scope fence + L2 round trip) -> fusion regressed 306->1221 us.
// Separate kernels (this form) measured 306 us total.
__launch_bounds__(384, 1)
__global__ void k_chain1(const float* __restrict__ GI1,
                         const u16* __restrict__ WHH1h,
                         const float* __restrict__ BHH1,
                         const float* __restrict__ H1I,
                         float* __restrict__ H1ALL)
{
  const int b = blockIdx.x;
  const int tid = threadIdx.x;
  __shared__ __align__(16) float h[128];
  __shared__ __align__(16) u16 hh[128];
  __shared__ float gh[384];
  if (tid < 128){ float v = H1I[b*128 + tid]; h[tid] = v; hh[tid] = f2h(v); }
  const float bias = BHH1[tid];
  u32 W[64];
  {
    const uint4* wp = (const uint4*)(WHH1h + tid*128);
    #pragma unroll
    for (int i = 0; i < 16; i++){
      uint4 v = wp[i];
      W[4*i] = v.x; W[4*i+1] = v.y; W[4*i+2] = v.z; W[4*i+3] = v.w;
    }
  }
  float cur[4][3] = {}, nxt[4][3] = {}, st[4] = {};
  if (tid < 128){
    #pragma unroll
    for (int i = 0; i < 4; i++){
      const float* gp = GI1 + (i*32 + b)*384;
      cur[i][0] = gp[tid]; cur[i][1] = gp[128+tid]; cur[i][2] = gp[256+tid];
    }
  }
  __syncthreads();
  for (int t0 = 0; t0 < T_; t0 += 4){
    if (tid < 128){
      #pragma unroll
      for (int i = 0; i < 4; i++){
        int tt = t0 + 4 + i;
        if (tt < T_){
          const float* gp = GI1 + (tt*32 + b)*384;
          nxt[i][0] = gp[tid]; nxt[i][1] = gp[128+tid]; nxt[i][2] = gp[256+tid];
        }
      }
    }
    #pragma unroll
    for (int ph = 0; ph < 4; ph++){
      if (t0 + ph >= T_) break;
      float a = bias, ab = 0.f;
      #pragma unroll
      for (int i = 0; i < 16; i++){
        uint4 hv = *(const uint4*)(hh + i*8);
        a  = dot2f(W[4*i],   hv.x, a);
        ab = dot2f(W[4*i+1], hv.y, ab);
        a  = dot2f(W[4*i+2], hv.z, a);
        ab = dot2f(W[4*i+3], hv.w, ab);
      }
      gh[tid] = a + ab;
      __syncthreads();
      if (tid < 128){
        float r = fast_sigmoid(cur[ph][0] + gh[tid]);
        float z = fast_sigmoid(cur[ph][1] + gh[128+tid]);
        float n = fast_tanh(cur[ph][2] + r*gh[256+tid]);
        float hn = (1.f - z)*n + z*h[tid];
        h[tid] = hn; hh[tid] = f2h(hn);
        st[ph] = hn;
      }
      __syncthreads();
    }
    if (tid < 128){
      #pragma unroll
      for (int ph = 0; ph < 4; ph++){
        int t = t0 + ph;
        if (t < T_) H1ALL[(t*32 + b)*128 + tid] = st[ph];
      }
      #pragma unroll
      for (int i = 0; i < 4; i++){
        cur[i][0] = nxt[i][0]; cur[i][1] = nxt[i][1]; cur[i][2] = nxt[i][2];
      }
    }
  }
}

// ---------------------------------------------------------------- K4b: h2/g2 chain (f16 dot2, batched)
__launch_bounds__(384, 1)
__global__ void k_chain2(const float* __restrict__ GI2,
                         const u16* __restrict__ WHH2h,
                         const float* __restrict__ BHH2,
                         const float* __restrict__ H2I,
                         float* __restrict__ G2)
{
  const int b = blockIdx.x;
  const int tid = threadIdx.x;
  __shared__ __align__(16) float h[128];
  __shared__ __align__(16) u16 hh[128];
  __shared__ float gh[384];
  if (tid < 128){ float v = H2I[b*128 + tid]; h[tid] = v; hh[tid] = f2h(v); }
  const float bias = BHH2[tid];
  u32 W[64];
  {
    const uint4* wp = (const uint4*)(WHH2h + tid*128);
    #pragma unroll
    for (int i = 0; i < 16; i++){
      uint4 v = wp[i];
      W[4*i] = v.x; W[4*i+1] = v.y; W[4*i+2] = v.z; W[4*i+3] = v.w;
    }
  }
  float cur[4][3] = {}, nxt[4][3] = {}, st[4] = {};
  if (tid < 128){
    #pragma unroll
    for (int i = 0; i < 4; i++){
      const float* gp = GI2 + (i*32 + b)*384;
      cur[i][0] = gp[tid]; cur[i][1] = gp[128+tid]; cur[i][2] = gp[256+tid];
    }
  }
  __syncthreads();
  for (int t0 = 0; t0 < T_; t0 += 4){
    if (tid < 128){
      #pragma unroll
      for (int i = 0; i < 4; i++){
        int tt = t0 + 4 + i;
        if (tt < T_){
          const float* gp = GI2 + (tt*32 + b)*384;
          nxt[i][0] = gp[tid]; nxt[i][1] = gp[128+tid]; nxt[i][2] = gp[256+tid];
        }
      }
    }
    #pragma unroll
    for (int ph = 0; ph < 4; ph++){
      const int t = t0 + ph;
      if (t >= T_) break;
      float a = bias, ab = 0.f;
      #pragma unroll
      for (int i = 0; i < 16; i++){
        uint4 hv = *(const uint4*)(hh + i*8);
        a  = dot2f(W[4*i],   hv.x, a);
        ab = dot2f(W[4*i+1], hv.y, ab);
        a  = dot2f(W[4*i+2], hv.z, a);
        ab = dot2f(W[4*i+3], hv.w, ab);
      }
      gh[tid] = a + ab;
      __syncthreads();
      if (tid < 128){
        float r2 = fast_sigmoid(cur[ph][0] + gh[tid]);
        float z2 = fast_sigmoid(cur[ph][1] + gh[128+tid]);
        float n2 = fast_tanh(cur[ph][2] + r2*gh[256+tid]);
        float g = (1.f - z2)*n2 + z2*h[tid];
        st[ph] = g;
        if (t > 0){ h[tid] = g; hh[tid] = f2h(g); }
      }
      __syncthreads();
    }
    if (tid < 128){
      #pragma unroll
      for (int ph = 0; ph < 4; ph++){
        int t = t0 + ph;
        if (t < T_) G2[(t*32 + b)*128 + tid] = st[ph];
      }
      #pragma unroll
      for (int i = 0; i < 4; i++){
        cur[i][0] = nxt[i][0]; cur[i][1] = nxt[i][1]; cur[i][2] = nxt[i][2];
      }
    }
  }
}

// ---------------------------------------------------------------- K5: Kp·w_k for all G2 rows (coalesced QWt)
__launch_bounds__(128, 4)
__global__ void k_kp(const float* __restrict__ G2,
                     const float* __restrict__ QWt, const float* __restrict__ QB,
                     const float* __restrict__ MW,
                     float* __restrict__ KPWG)
{
  __shared__ __align__(16) float X[8][128];
  __shared__ float red[8][2];
  const int tid = threadIdx.x;
  const int base = blockIdx.x * 8;
  for (int o = tid; o < 1024; o += 128){
    int r = o >> 7, c = o & 127;
    X[r][c] = G2[(base + r)*128 + c];
  }
  __syncthreads();
  float acc[8];
  float bias = QB[tid];
  #pragma unroll
  for (int r = 0; r < 8; r++) acc[r] = bias;
  const float4* wp = (const float4*)QWt;
  #pragma unroll 4
  for (int g = 0; g < 32; g++){
    float4 wv = wp[g*128 + tid];
    int kk = 4*g;
    #pragma unroll
    for (int r = 0; r < 8; r++){
      float4 t4 = *(const float4*)(&X[r][kk]);
      acc[r] = fmaf(t4.x, wv.x, acc[r]);
      acc[r] = fmaf(t4.y, wv.y, acc[r]);
      acc[r] = fmaf(t4.z, wv.z, acc[r]);
      acc[r] = fmaf(t4.w, wv.w, acc[r]);
    }
  }
  const float wk = MW[128 + tid];
  const int lane = tid & 63, wv_ = tid >> 6;
  #pragma unroll
  for (int r = 0; r < 8; r++){
    float pv = fast_tanh(acc[r]) * wk;
    for (int off = 32; off; off >>= 1) pv += __shfl_down(pv, off);
    if (lane == 0) red[r][wv_] = pv;
  }
  __syncthreads();
  if (tid < 8) KPWG[base + tid] = red[tid][0] + red[tid][1];
}

// ---------------------------------------------------------------- K6: predict + output
__global__ void k_pred(const int* __restrict__ question,
                       const int* __restrict__ qci, const void* __restrict__ qcm,
                       const int* __restrict__ flags,
                       const float* __restrict__ EQ, const float* __restrict__ EC,
                       const float* __restrict__ QB, const float* __restrict__ MW,
                       const float* __restrict__ G2,
                       const int* __restrict__ IDX,
                       const float* __restrict__ KPWG,
                       void* __restrict__ outp)
{
  const int blk = blockIdx.x;
  const int t = blk >> 5, b = blk & 31;
  const int tid = threadIdx.x;               // 64
  __shared__ float hist[11][132];
  __shared__ float qcs[128];
  __shared__ float og[11];
  __shared__ float kpw[11];
  __shared__ int   idxs[10];
  __shared__ float kpw0s;
  const int qid = question[b*S_ + t + 1];
  const int bflag = flags[1];
  if (tid < 10) idxs[tid] = IDX[blk*10 + tid];
  __syncthreads();
  for (int o = tid; o < 11*128; o += 64){
    int k = o >> 7, c = o & 127;
    float v;
    if (k == 0) v = G2[blk*128 + c];
    else { int s = idxs[k-1]; v = (s == 0) ? 0.f : G2[(s*32 + b)*128 + c]; }
    hist[k][c] = v;
  }
  #pragma unroll
  for (int o = tid; o < 128; o += 64){
    float v = EQ[qid*128 + o];
    #pragma unroll
    for (int q = 0; q < 4; q++){
      if (readBool(qcm, qid*4 + q, bflag))
        v += EC[qci[qid*4 + q]*128 + o];
    }
    qcs[o] = v;
  }
  {
    float pv = fast_tanh(QB[tid])      * MW[128 + tid]
             + fast_tanh(QB[tid + 64]) * MW[128 + tid + 64];
    for (int off = 32; off; off >>= 1) pv += __shfl_down(pv, off);
    if (tid == 0) kpw0s = pv;
  }
  __syncthreads();
  if (tid < 11){
    float acc = 0.f;
    for (int c = 0; c < 128; c++) acc = fmaf(qcs[c], hist[tid][c], acc);
    og[tid] = acc;
    float v;
    if (tid == 0) v = KPWG[blk];
    else { int s = idxs[tid-1]; v = (s == 0) ? kpw0s : KPWG[s*32 + b]; }
    kpw[tid] = v;
  }
  __syncthreads();
  if (tid == 0){
    float tv[11];
    #pragma unroll
    for (int k = 0; k < 11; k++){
      int valid = (k == 0) || (idxs[k-1] < t);
      tv[k] = valid ? kpw[k] : NEGV;
    }
    float m = tv[0];
    #pragma unroll
    for (int k = 1; k < 11; k++) m = fmaxf(m, tv[k]);
    float den = 0.f, num = 0.f;
    #pragma unroll
    for (int k = 0; k < 11; k++){
      float e = __expf(tv[k] - m);
      den += e;
      num = fmaf(e, og[k], num);
    }
    float p = num / den;
    int col = (t == 0) ? 0 : (t + 1);
    if (flags[0]){
      ((float*)outp)[b*S_ + col] = p;
      if (t == 0) ((float*)outp)[b*S_ + 1] = 0.f;
    } else {
      ((u16*)outp)[b*S_ + col] = f2bf(p);
      if (t == 0) ((u16*)outp)[b*S_ + 1] = (u16)0;
    }
  }
}

// ---------------------------------------------------------------- launcher
extern "C" void kernel_launch(void* const* d_in, const int* in_sizes, int n_in,
                              void* d_out, int out_size, void* d_ws, size_t ws_size,
                              hipStream_t stream)
{
  (void)in_sizes; (void)n_in; (void)out_size; (void)ws_size;
  const int* question      = (const int*)d_in[0];
  const int* response      = (const int*)d_in[1];
  const void* maskp        = d_in[2];
  const int* q_neighbors   = (const int*)d_in[3];
  const int* s_neighbors   = (const int*)d_in[4];
  const int* q_concept_idx = (const int*)d_in[5];
  const void* q_concept_mask = d_in[6];

  static const int CN[NCVT] = {2560000,256000,256,98304,49152,384,384,49152,49152,
                               384,384,49152,384,16384,128,16384,128,16384,128,
                               256,1,4096,4096};
  CvtArgs ca;
  int off = 0;
  for (int i = 0; i < NCVT; i++){
    ca.s[i] = d_in[7 + i];
    ca.nreal[i] = CN[i];
    ca.off[i] = off;
    off += (CN[i] + 3) & ~3;
  }
  ca.off[NCVT] = off;
  const int total = off;

  char* ws = (char*)d_ws;
  size_t wo = 0;
  auto alloc = [&](size_t bytes) -> void* {
    void* p = ws + wo;
    wo = (wo + bytes + 255) & ~(size_t)255;
    return p;
  };
  int*   flags = (int*)  alloc(16);
  float* CVT   = (float*)alloc((size_t)total * 4);
  float* EQREC = (float*)alloc((size_t)B_*S_*D_*4);
  float* GI1   = (float*)alloc((size_t)T_*B_*384*4);
  float* GI2A  = (float*)alloc((size_t)T_*B_*384*4);
  float* H1ALL = (float*)alloc((size_t)T_*B_*D_*4);
  float* G2    = (float*)alloc((size_t)T_*B_*D_*4);
  int*   IDX   = (int*)  alloc((size_t)T_*B_*10*4);
  float* KPWG  = (float*)alloc((size_t)T_*B_*4);
  float* KHG   = (float*)alloc((size_t)B_*S_*D_*4);
  u16*   WHH1h = (u16*)  alloc(49152*2);
  u16*   WHH2h = (u16*)  alloc(49152*2);
  u32*   AWt   = (u32*)  alloc(24576*4);
  u32*   ALWt  = (u32*)  alloc(8192*4);
  u32*   WIH1t = (u32*)  alloc(49152*4);
  u32*   WIH2t = (u32*)  alloc(24576*4);
  float* QWt   = (float*)alloc(16384*4);

  const float* EQ   = CVT + ca.off[0];
  const float* EC   = CVT + ca.off[1];
  const float* ECOR = CVT + ca.off[2];
  const float* WIH1 = CVT + ca.off[3];
  const float* WHH1 = CVT + ca.off[4];
  const float* BIH1 = CVT + ca.off[5];
  const float* BHH1 = CVT + ca.off[6];
  const float* WIH2 = CVT + ca.off[7];
  const float* WHH2 = CVT + ca.off[8];
  const float* BIH2 = CVT + ca.off[9];
  const float* BHH2 = CVT + ca.off[10];
  const float* AW   = CVT + ca.off[11];
  const float* AB   = CVT + ca.off[12];
  const float* ALW  = CVT + ca.off[13];
  const float* ALB  = CVT + ca.off[14];
  const float* QW   = CVT + ca.off[15];
  const float* QB   = CVT + ca.off[16];
  const float* MW   = CVT + ca.off[19];
  const float* H1I  = CVT + ca.off[21];
  const float* H2I  = CVT + ca.off[22];

  k_sniff2<<<1, 256, 0, stream>>>((const u16*)d_in[7], (const unsigned char*)maskp, flags);
  k_cvt<<<(total + 255)/256, 256, 0, stream>>>(ca, flags, CVT);
  k_prep<<<192, 256, 0, stream>>>(WHH1, WHH2, AW, ALW, WIH1, WIH2, QW,
                                  WHH1h, WHH2h, AWt, ALWt, WIH1t, WIH2t, QWt);
  k_khg<<<(B_*S_*D_ + 255)/256, 256, 0, stream>>>(question, EQ, KHG);
  k_agg<<<B_*S_/2, 256, 0, stream>>>(question, q_neighbors, s_neighbors, EQ, EC,
                                     AWt, AB, ALWt, ALB, maskp, flags, EQREC);
  k_gi1<<<dim3(T_, 4), 384, 0, stream>>>(EQREC, response, ECOR, WIH1t, BIH1, GI1);
  k_topk<<<T_*B_, 64, 0, stream>>>(KHG, IDX);
  k_chain1<<<B_, 384, 0, stream>>>(GI1, WHH1h, BHH1, H1I, H1ALL);
  k_gi2<<<dim3(T_, 4), 384, 0, stream>>>(H1ALL, WIH2t, BIH2, GI2A);
  k_chain2<<<B_, 384, 0, stream>>>(GI2A, WHH2h, BHH2, H2I, G2);
  k_kp<<<T_*B_/8, 128, 0, stream>>>(G2, QWt, QB, MW, KPWG);
  k_pred<<<T_*B_, 64, 0, stream>>>(question, q_concept_idx, q_concept_mask, flags,
                                   EQ, EC, QB, MW, G2, IDX, KPWG, d_out);
}

// Round 15
// 770.682 us; speedup vs baseline: 2.2105x; 1.0172x over previous
//
#include <hip/hip_runtime.h>
#include <math.h>

typedef unsigned short u16;
typedef unsigned int   u32;
typedef __attribute__((ext_vector_type(2))) _Float16 half2_t;

#define B_   32
#define S_   200
#define D_   128
#define T_   199
#define NEGV (-1e30f)

__device__ __forceinline__ float bf2f(u16 u){
  union { u32 i; float f; } v; v.i = ((u32)u) << 16; return v.f;
}
__device__ __forceinline__ u16 f2bf(float f){
  union { float f; u32 i; } v; v.f = f;
  u32 x = v.i;
  return (u16)((x + 0x7fffu + ((x >> 16) & 1u)) >> 16);   // RNE
}
__device__ __forceinline__ u16 f2h(float x){
  union { _Float16 h; u16 u; } v; v.h = (_Float16)x; return v.u;
}
__device__ __forceinline__ float h2f(u16 u){
  union { u16 u; _Float16 h; } v; v.u = u; return (float)v.h;
}
__device__ __forceinline__ u32 pkh(float lo, float hi){
  return ((u32)f2h(hi) << 16) | f2h(lo);
}
__device__ __forceinline__ float dot2f(u32 w, u32 h, float acc){
#if __has_builtin(__builtin_amdgcn_fdot2)
  union { u32 u; half2_t h2; } a, b;
  a.u = w; b.u = h;
  return __builtin_amdgcn_fdot2(a.h2, b.h2, acc, false);
#else
  union { u32 u; _Float16 f[2]; } a, b;
  a.u = w; b.u = h;
  acc = fmaf((float)a.f[0], (float)b.f[0], acc);
  return fmaf((float)a.f[1], (float)b.f[1], acc);
#endif
}
__device__ __forceinline__ float fast_sigmoid(float x){ return 1.f/(1.f+__expf(-x)); }
__device__ __forceinline__ float fast_tanh(float x){
  float e = __expf(2.f*x);
  return 1.f - 2.f/(e + 1.f);
}

// bool storage modes: 0=int32, 1=u8, 2=bf16, 3=f32
__device__ __forceinline__ int readBool(const void* p, int i, int m){
  if (m == 0) return ((const int*)p)[i] != 0;
  if (m == 1) return ((const unsigned char*)p)[i] != 0;
  if (m == 2) return ((const u16*)p)[i] != 0;
  return ((const u32*)p)[i] != 0;
}

__device__ __forceinline__ float dot128f(const float* __restrict__ w,
                                         const float* __restrict__ x){
  float acc = 0.f;
  const float4* wp = (const float4*)w;
  #pragma unroll 8
  for (int i = 0; i < 32; i++){
    float4 v = wp[i]; int k = 4*i;
    acc = fmaf(v.x, x[k],   acc);
    acc = fmaf(v.y, x[k+1], acc);
    acc = fmaf(v.z, x[k+2], acc);
    acc = fmaf(v.w, x[k+3], acc);
  }
  return acc;
}

// scalar LDS dot (rows at odd stride -> bank-conflict-free, unaligned ok)
__device__ __forceinline__ float dotLDS(const float* __restrict__ row,
                                        const float* __restrict__ qn){
  float a0 = 0.f, a1 = 0.f, a2 = 0.f, a3 = 0.f;
  #pragma unroll 8
  for (int k = 0; k < 128; k += 4){
    a0 = fmaf(row[k],   qn[k],   a0);
    a1 = fmaf(row[k+1], qn[k+1], a1);
    a2 = fmaf(row[k+2], qn[k+2], a2);
    a3 = fmaf(row[k+3], qn[k+3], a3);
  }
  return (a0 + a1) + (a2 + a3);
}

// ---------------------------------------------------------------- sniffer
__global__ void k_sniff2(const u16* __restrict__ embq_raw,
                         const unsigned char* __restrict__ mask_raw,
                         int* __restrict__ flags){
  __shared__ int bad, gt1, m4, b0;
  const int tid = threadIdx.x;
  if (tid == 0){ bad = 0; gt1 = 0; m4 = 0; b0 = 0; }
  __syncthreads();
  for (int i = tid; i < 512; i += 256){
    u16 u = embq_raw[i];
    if (u){ int e = (u >> 7) & 0xFF; if (e < 0x58 || e > 0x7F) atomicAdd(&bad, 1); }
  }
  for (int i = tid; i < 1024; i += 256){
    unsigned char c = mask_raw[i];
    if (c > 1) atomicAdd(&gt1, 1);
    if (c && (i & 3)) atomicAdd(&m4, 1);
    if (c && !(i & 3)) atomicAdd(&b0, 1);
  }
  __syncthreads();
  if (tid == 0){
    flags[0] = (bad >= 16) ? 1 : 0;
    flags[1] = gt1 ? (b0 ? 2 : 3) : (m4 ? 1 : 0);
  }
}

// ---------------------------------------------------------------- convert floats -> f32
#define NCVT 23
struct CvtArgs { const void* s[NCVT]; int off[NCVT+1]; int nreal[NCVT]; };

__global__ void k_cvt(CvtArgs a, const int* __restrict__ flags, float* __restrict__ dst){
  __shared__ int f;
  if (threadIdx.x == 0) f = flags[0];
  __syncthreads();
  int gid = blockIdx.x * 256 + threadIdx.x;
  if (gid >= a.off[NCVT]) return;
  int ai = 0;
  for (int i = 1; i < NCVT; i++) if (gid >= a.off[i]) ai = i;
  int i = gid - a.off[ai];
  float v = 0.f;
  if (i < a.nreal[ai])
    v = f ? ((const float*)a.s[ai])[i] : bf2f(((const u16*)a.s[ai])[i]);
  dst[gid] = v;
}

// ---------------------------------------------------------------- prep (transposed/coalesced weights)
__global__ void k_prep(const float* __restrict__ WHH1, const float* __restrict__ WHH2,
                       const float* __restrict__ AW,   const float* __restrict__ ALW,
                       const float* __restrict__ WIH1, const float* __restrict__ WIH2,
                       const float* __restrict__ QW,
                       u16* __restrict__ WHH1h, u16* __restrict__ WHH2h,
                       u32* __restrict__ AWt,   u32* __restrict__ ALWt,
                       u32* __restrict__ WIH1t, u32* __restrict__ WIH2t,
                       float* __restrict__ QWt)
{
  const int gid0 = blockIdx.x*256 + threadIdx.x;
  const int stride = gridDim.x*256;
  for (int g = gid0; g < 49152; g += stride){
    WHH1h[g] = f2h(WHH1[g]);
    WHH2h[g] = f2h(WHH2[g]);
  }
  for (int g = gid0; g < 24576; g += stride){
    int s = g >> 13, w = g & 8191;
    int k8 = w >> 9, r = w & 511, c = r >> 2, j = r & 3;
    const float* b = AW + s*16384 + c*128 + k8*8 + 2*j;
    AWt[g] = pkh(b[0], b[1]);
  }
  for (int g = gid0; g < 8192; g += stride){
    int k8 = g >> 9, r = g & 511, c = r >> 2, j = r & 3;
    const float* b = ALW + c*128 + k8*8 + 2*j;
    ALWt[g] = pkh(b[0], b[1]);
  }
  for (int g = gid0; g < 49152; g += stride){
    int k8 = g / 1536, r = g % 1536, c = r >> 2, j = r & 3;
    const float* b = WIH1 + c*256 + k8*8 + 2*j;
    WIH1t[g] = pkh(b[0], b[1]);
  }
  for (int g = gid0; g < 24576; g += stride){
    int k8 = g / 1536, r = g % 1536, c = r >> 2, j = r & 3;
    const float* b = WIH2 + c*128 + k8*8 + 2*j;
    WIH2t[g] = pkh(b[0], b[1]);
  }
  for (int g = gid0; g < 16384; g += stride){
    int k4 = g >> 9, r = g & 511, c = r >> 2, j = r & 3;
    QWt[g] = QW[c*128 + k4*4 + j];
  }
}

// ---------------------------------------------------------------- khg: K_hist pre-gather (coalesced)
__global__ void k_khg(const int* __restrict__ question,
                      const float* __restrict__ EQ,
                      float* __restrict__ KHG)
{
  int o = blockIdx.x*256 + threadIdx.x;
  if (o < B_*S_*D_){
    int row = o >> 7;
    KHG[o] = EQ[question[row]*128 + (o & 127)];
  }
}

// ---------------------------------------------------------------- K1: hop aggregation (f16 dot2, coalesced Wt)
template<int ROWS>
__device__ __forceinline__ void agg_stage_h(const u16* __restrict__ tmph,
    const u32* __restrict__ Wt, const float* __restrict__ bg,
    u16* __restrict__ outh, int c)
{
  float bias = bg[c];
  float acc[ROWS];
  #pragma unroll
  for (int r = 0; r < ROWS; r++) acc[r] = bias;
  const uint4* wp = (const uint4*)Wt;
  if constexpr (ROWS <= 4){
    float acc2[ROWS];
    #pragma unroll
    for (int r = 0; r < ROWS; r++) acc2[r] = 0.f;
    #pragma unroll 4
    for (int g = 0; g < 16; g++){
      uint4 wv = wp[g*128 + c];
      #pragma unroll
      for (int r = 0; r < ROWS; r++){
        uint4 hv = *(const uint4*)(tmph + r*128 + g*8);
        acc[r]  = dot2f(wv.x, hv.x, acc[r]);
        acc2[r] = dot2f(wv.y, hv.y, acc2[r]);
        acc[r]  = dot2f(wv.z, hv.z, acc[r]);
        acc2[r] = dot2f(wv.w, hv.w, acc2[r]);
      }
    }
    #pragma unroll
    for (int r = 0; r < ROWS; r++)
      outh[r*128 + c] = f2h(fast_tanh(acc[r] + acc2[r]));
  } else {
    #pragma unroll 4
    for (int g = 0; g < 16; g++){
      uint4 wv = wp[g*128 + c];
      #pragma unroll
      for (int r = 0; r < ROWS; r++){
        uint4 hv = *(const uint4*)(tmph + r*128 + g*8);
        acc[r] = dot2f(wv.x, hv.x, acc[r]);
        acc[r] = dot2f(wv.y, hv.y, acc[r]);
        acc[r] = dot2f(wv.z, hv.z, acc[r]);
        acc[r] = dot2f(wv.w, hv.w, acc[r]);
      }
    }
    #pragma unroll
    for (int r = 0; r < ROWS; r++)
      outh[r*128 + c] = f2h(fast_tanh(acc[r]));
  }
}

__launch_bounds__(256, 4)
__global__ void k_agg(const int* __restrict__ question,
                      const int* __restrict__ q_neighbors,
                      const int* __restrict__ s_neighbors,
                      const float* __restrict__ EQ,
                      const float* __restrict__ EC,
                      const u32* __restrict__ AWt,
                      const float* __restrict__ AB,
                      const u32* __restrict__ ALWt,
                      const float* __restrict__ ALB,
                      const void* __restrict__ maskp,
                      const int* __restrict__ flags,
                      float* __restrict__ EQREC)
{
  __shared__ __align__(16) u16 e0h[2][128];
  __shared__ __align__(16) u16 e1h[2][512];
  __shared__ __align__(16) u16 e2h[2][2048];
  __shared__ __align__(16) u16 tmph[2][2048];
  __shared__ int nn1[2][4]; __shared__ int nn2[2][16]; __shared__ int nn3[2][64];
  const int tid  = threadIdx.x;
  const int c    = tid & 127;
  const int half = tid >> 7;
  const int bs   = blockIdx.x*2 + half;
  const int n0   = question[bs];
  u16* tp = tmph[half];

  if (c < 4) nn1[half][c] = q_neighbors[n0*4 + c];
  __syncthreads();
  if (c < 16) nn2[half][c] = s_neighbors[nn1[half][c>>2]*4 + (c&3)];
  __syncthreads();
  if (c < 64) nn3[half][c] = q_neighbors[nn2[half][c>>2]*4 + (c&3)];
  e0h[half][c] = f2h(EQ[n0*128 + c]);
  #pragma unroll
  for (int r = 0; r < 4; r++)  e1h[half][r*128 + c] = f2h(EC[nn1[half][r]*128 + c]);
  #pragma unroll 4
  for (int r = 0; r < 16; r++) e2h[half][r*128 + c] = f2h(EQ[nn2[half][r]*128 + c]);
  __syncthreads();

  auto fill_e0 = [&](){
    float v = 0.25f*(h2f(e1h[half][c]) + h2f(e1h[half][128+c])
                   + h2f(e1h[half][256+c]) + h2f(e1h[half][384+c]))
            + h2f(e0h[half][c]);
    tp[c] = f2h(v);
  };
  auto fill_e1 = [&](){
    #pragma unroll
    for (int r = 0; r < 4; r++){
      float v = 0.25f*(h2f(e2h[half][(4*r)*128+c])   + h2f(e2h[half][(4*r+1)*128+c])
                     + h2f(e2h[half][(4*r+2)*128+c]) + h2f(e2h[half][(4*r+3)*128+c]))
              + h2f(e1h[half][r*128 + c]);
      tp[r*128 + c] = f2h(v);
    }
  };

  fill_e0(); __syncthreads();
  agg_stage_h<1>(tp, AWt, AB, e0h[half], c); __syncthreads();
  fill_e1(); __syncthreads();
  agg_stage_h<4>(tp, AWt + 8192, AB + 128, e1h[half], c); __syncthreads();
  #pragma unroll 2
  for (int r = 0; r < 16; r++){
    float m = 0.25f*( EC[nn3[half][4*r]*128+c]   + EC[nn3[half][4*r+1]*128+c]
                    + EC[nn3[half][4*r+2]*128+c] + EC[nn3[half][4*r+3]*128+c] );
    tp[r*128 + c] = f2h(m + h2f(e2h[half][r*128 + c]));
  }
  __syncthreads();
  agg_stage_h<16>(tp, AWt + 16384, AB + 256, e2h[half], c); __syncthreads();
  fill_e0(); __syncthreads();
  agg_stage_h<1>(tp, AWt, AB, e0h[half], c); __syncthreads();
  fill_e1(); __syncthreads();
  agg_stage_h<4>(tp, AWt + 8192, AB + 128, e1h[half], c); __syncthreads();
  fill_e0(); __syncthreads();
  agg_stage_h<1>(tp, AWt, AB, e0h[half], c); __syncthreads();
  agg_stage_h<1>(e0h[half], ALWt, ALB, tp, c); __syncthreads();
  const int msk = readBool(maskp, bs, flags[1]);
  EQREC[bs*128 + c] = msk ? h2f(tp[c]) : EQ[n0*128 + c];
}

// ---------------------------------------------------------------- K2: gi1 precompute (K=256, f16 dot2, coalesced)
__launch_bounds__(384, 1)
__global__ void k_gi1(const float* __restrict__ EQREC,
                      const int* __restrict__ response,
                      const float* __restrict__ ECOR,
                      const u32* __restrict__ WIH1t,
                      const float* __restrict__ BIH1,
                      float* __restrict__ GI1)
{
  const int t  = blockIdx.x;
  const int bg = blockIdx.y;
  const int tid = threadIdx.x;
  __shared__ __align__(16) u16 X[8][256];
  for (int o = tid; o < 2048; o += 384){
    int bb = o >> 8, k = o & 255;
    int b = bg*8 + bb;
    float v = (k < 128) ? EQREC[(b*S_ + t)*128 + k]
                        : ECOR[response[b*S_ + t]*128 + (k - 128)];
    X[bb][k] = f2h(v);
  }
  __syncthreads();
  float bias = BIH1[tid];
  float acc[8];
  #pragma unroll
  for (int i = 0; i < 8; i++) acc[i] = bias;
  const uint4* wp = (const uint4*)WIH1t;
  #pragma unroll 4
  for (int g = 0; g < 32; g++){
    uint4 wv = wp[g*384 + tid];
    #pragma unroll
    for (int bb = 0; bb < 8; bb++){
      uint4 hv = *(const uint4*)(&X[bb][g*8]);
      acc[bb] = dot2f(wv.x, hv.x, acc[bb]);
      acc[bb] = dot2f(wv.y, hv.y, acc[bb]);
      acc[bb] = dot2f(wv.z, hv.z, acc[bb]);
      acc[bb] = dot2f(wv.w, hv.w, acc[bb]);
    }
  }
  #pragma unroll
  for (int bb = 0; bb < 8; bb++)
    GI1[(t*32 + bg*8 + bb)*384 + tid] = acc[bb];
}

// ---------------------------------------------------------------- K2b: gi2 precompute (K=128, f16 dot2, coalesced)
__launch_bounds__(384, 1)
__global__ void k_gi2(const float* __restrict__ H1ALL,
                      const u32* __restrict__ WIH2t,
                      const float* __restrict__ BIH2,
                      float* __restrict__ GI2)
{
  const int t  = blockIdx.x;
  const int bg = blockIdx.y;
  const int tid = threadIdx.x;
  __shared__ __align__(16) u16 X[8][128];
  for (int o = tid; o < 1024; o += 384){
    int bb = o >> 7, k = o & 127;
    int b = bg*8 + bb;
    X[bb][k] = f2h(H1ALL[(t*32 + b)*128 + k]);
  }
  __syncthreads();
  float bias = BIH2[tid];
  float acc[8];
  #pragma unroll
  for (int i = 0; i < 8; i++) acc[i] = bias;
  const uint4* wp = (const uint4*)WIH2t;
  #pragma unroll 4
  for (int g = 0; g < 16; g++){
    uint4 wv = wp[g*384 + tid];
    #pragma unroll
    for (int bb = 0; bb < 8; bb++){
      uint4 hv = *(const uint4*)(&X[bb][g*8]);
      acc[bb] = dot2f(wv.x, hv.x, acc[bb]);
      acc[bb] = dot2f(wv.y, hv.y, acc[bb]);
      acc[bb] = dot2f(wv.z, hv.z, acc[bb]);
      acc[bb] = dot2f(wv.w, hv.w, acc[bb]);
    }
  }
  #pragma unroll
  for (int bb = 0; bb < 8; bb++)
    GI2[(t*32 + bg*8 + bb)*384 + tid] = acc[bb];
}

// ---------------------------------------------------------------- K3: scores + top-10
// LDS tile with ODD row stride 129: bank = (129*s + k) % 32 = (s+k) % 32 ->
// lanes (distinct s) hit distinct banks -> conflict-free. r14's stride-128
// tile had all 64 lanes on ONE bank (1.87e7 conflicts, 221 us).
#define NA_  127
#define STR_ 129
__global__ void k_topk(const float* __restrict__ KHG,
                       int* __restrict__ IDX)
{
  const int blk = blockIdx.x;
  const int t = blk >> 5, b = blk & 31;
  const int tid = threadIdx.x;               // 64
  __shared__ float tile[NA_*STR_];           // 65532 B
  __shared__ __align__(16) float qn[128];
  const float* KB_ = KHG + (size_t)b*S_*128;
  for (int o = tid; o < 128; o += 64) qn[o] = KB_[(t+1)*128 + o];
  const int nA = (t < NA_) ? t : NA_;
  for (int o = tid; o < nA*128; o += 64){
    int s = o >> 7, c = o & 127;
    tile[s*STR_ + c] = KB_[o];
  }
  __syncthreads();
  float val[4]; int sv[4];
  #pragma unroll
  for (int i = 0; i < 4; i++){
    int s = tid + 64*i;
    sv[i] = s;
    float v = -3.0e38f;
    if (s < S_){
      if (s >= t) v = NEGV;
      else if (s < nA) v = dotLDS(tile + s*STR_, qn);
    }
    val[i] = v;
  }
  if (t > NA_){                              // pass B: rows [NA_, t)
    __syncthreads();
    int nB = t - NA_;
    for (int o = tid; o < nB*128; o += 64){
      int s = o >> 7, c = o & 127;
      tile[s*STR_ + c] = KB_[(NA_ + s)*128 + c];
    }
    __syncthreads();
    #pragma unroll
    for (int i = 1; i < 4; i++){
      int s = tid + 64*i;
      if (s >= NA_ && s < t) val[i] = dotLDS(tile + (s-NA_)*STR_, qn);
    }
  }
  for (int r = 0; r < 10; r++){
    float bv = -3.0e38f; int bi = 0x3fffffff;
    #pragma unroll
    for (int i = 0; i < 4; i++){
      if (val[i] > bv || (val[i] == bv && sv[i] < bi)){ bv = val[i]; bi = sv[i]; }
    }
    for (int off = 32; off; off >>= 1){
      float ov = __shfl_down(bv, off);
      int   oi = __shfl_down(bi, off);
      if (ov > bv || (ov == bv && oi < bi)){ bv = ov; bi = oi; }
    }
    int win = __shfl(bi, 0);
    if (tid == 0) IDX[blk*10 + r] = win;
    #pragma unroll
    for (int i = 0; i < 4; i++) if (sv[i] == win) val[i] = -3.0e38f;
  }
}

// ---------------------------------------------------------------- K4a: h1 chain (f16 dot2, batched groups of 4)
// r13 lesson: cross-block producer/consumer flags cost ~24 us/hop on MI355X
// -> keep the three chain-stage kernels separate (306 us total).
__launch_bounds__(384, 1)
__global__ void k_chain1(const float* __restrict__ GI1,
                         const u16* __restrict__ WHH1h,
                         const float* __restrict__ BHH1,
                         const float* __restrict__ H1I,
                         float* __restrict__ H1ALL)
{
  const int b = blockIdx.x;
  const int tid = threadIdx.x;
  __shared__ __align__(16) float h[128];
  __shared__ __align__(16) u16 hh[128];
  __shared__ float gh[384];
  if (tid < 128){ float v = H1I[b*128 + tid]; h[tid] = v; hh[tid] = f2h(v); }
  const float bias = BHH1[tid];
  u32 W[64];
  {
    const uint4* wp = (const uint4*)(WHH1h + tid*128);
    #pragma unroll
    for (int i = 0; i < 16; i++){
      uint4 v = wp[i];
      W[4*i] = v.x; W[4*i+1] = v.y; W[4*i+2] = v.z; W[4*i+3] = v.w;
    }
  }
  float cur[4][3] = {}, nxt[4][3] = {}, st[4] = {};
  if (tid < 128){
    #pragma unroll
    for (int i = 0; i < 4; i++){
      const float* gp = GI1 + (i*32 + b)*384;
      cur[i][0] = gp[tid]; cur[i][1] = gp[128+tid]; cur[i][2] = gp[256+tid];
    }
  }
  __syncthreads();
  for (int t0 = 0; t0 < T_; t0 += 4){
    if (tid < 128){
      #pragma unroll
      for (int i = 0; i < 4; i++){
        int tt = t0 + 4 + i;
        if (tt < T_){
          const float* gp = GI1 + (tt*32 + b)*384;
          nxt[i][0] = gp[tid]; nxt[i][1] = gp[128+tid]; nxt[i][2] = gp[256+tid];
        }
      }
    }
    #pragma unroll
    for (int ph = 0; ph < 4; ph++){
      if (t0 + ph >= T_) break;
      float a = bias, ab = 0.f;
      #pragma unroll
      for (int i = 0; i < 16; i++){
        uint4 hv = *(const uint4*)(hh + i*8);
        a  = dot2f(W[4*i],   hv.x, a);
        ab = dot2f(W[4*i+1], hv.y, ab);
        a  = dot2f(W[4*i+2], hv.z, a);
        ab = dot2f(W[4*i+3], hv.w, ab);
      }
      gh[tid] = a + ab;
      __syncthreads();
      if (tid < 128){
        float r = fast_sigmoid(cur[ph][0] + gh[tid]);
        float z = fast_sigmoid(cur[ph][1] + gh[128+tid]);
        float n = fast_tanh(cur[ph][2] + r*gh[256+tid]);
        float hn = (1.f - z)*n + z*h[tid];
        h[tid] = hn; hh[tid] = f2h(hn);
        st[ph] = hn;
      }
      __syncthreads();
    }
    if (tid < 128){
      #pragma unroll
      for (int ph = 0; ph < 4; ph++){
        int t = t0 + ph;
        if (t < T_) H1ALL[(t*32 + b)*128 + tid] = st[ph];
      }
      #pragma unroll
      for (int i = 0; i < 4; i++){
        cur[i][0] = nxt[i][0]; cur[i][1] = nxt[i][1]; cur[i][2] = nxt[i][2];
      }
    }
  }
}

// ---------------------------------------------------------------- K4b: h2/g2 chain (f16 dot2, batched)
__launch_bounds__(384, 1)
__global__ void k_chain2(const float* __restrict__ GI2,
                         const u16* __restrict__ WHH2h,
                         const float* __restrict__ BHH2,
                         const float* __restrict__ H2I,
                         float* __restrict__ G2)
{
  const int b = blockIdx.x;
  const int tid = threadIdx.x;
  __shared__ __align__(16) float h[128];
  __shared__ __align__(16) u16 hh[128];
  __shared__ float gh[384];
  if (tid < 128){ float v = H2I[b*128 + tid]; h[tid] = v; hh[tid] = f2h(v); }
  const float bias = BHH2[tid];
  u32 W[64];
  {
    const uint4* wp = (const uint4*)(WHH2h + tid*128);
    #pragma unroll
    for (int i = 0; i < 16; i++){
      uint4 v = wp[i];
      W[4*i] = v.x; W[4*i+1] = v.y; W[4*i+2] = v.z; W[4*i+3] = v.w;
    }
  }
  float cur[4][3] = {}, nxt[4][3] = {}, st[4] = {};
  if (tid < 128){
    #pragma unroll
    for (int i = 0; i < 4; i++){
      const float* gp = GI2 + (i*32 + b)*384;
      cur[i][0] = gp[tid]; cur[i][1] = gp[128+tid]; cur[i][2] = gp[256+tid];
    }
  }
  __syncthreads();
  for (int t0 = 0; t0 < T_; t0 += 4){
    if (tid < 128){
      #pragma unroll
      for (int i = 0; i < 4; i++){
        int tt = t0 + 4 + i;
        if (tt < T_){
          const float* gp = GI2 + (tt*32 + b)*384;
          nxt[i][0] = gp[tid]; nxt[i][1] = gp[128+tid]; nxt[i][2] = gp[256+tid];
        }
      }
    }
    #pragma unroll
    for (int ph = 0; ph < 4; ph++){
      const int t = t0 + ph;
      if (t >= T_) break;
      float a = bias, ab = 0.f;
      #pragma unroll
      for (int i = 0; i < 16; i++){
        uint4 hv = *(const uint4*)(hh + i*8);
        a  = dot2f(W[4*i],   hv.x, a);
        ab = dot2f(W[4*i+1], hv.y, ab);
        a  = dot2f(W[4*i+2], hv.z, a);
        ab = dot2f(W[4*i+3], hv.w, ab);
      }
      gh[tid] = a + ab;
      __syncthreads();
      if (tid < 128){
        float r2 = fast_sigmoid(cur[ph][0] + gh[tid]);
        float z2 = fast_sigmoid(cur[ph][1] + gh[128+tid]);
        float n2 = fast_tanh(cur[ph][2] + r2*gh[256+tid]);
        float g = (1.f - z2)*n2 + z2*h[tid];
        st[ph] = g;
        if (t > 0){ h[tid] = g; hh[tid] = f2h(g); }
      }
      __syncthreads();
    }
    if (tid < 128){
      #pragma unroll
      for (int ph = 0; ph < 4; ph++){
        int t = t0 + ph;
        if (t < T_) G2[(t*32 + b)*128 + tid] = st[ph];
      }
      #pragma unroll
      for (int i = 0; i < 4; i++){
        cur[i][0] = nxt[i][0]; cur[i][1] = nxt[i][1]; cur[i][2] = nxt[i][2];
      }
    }
  }
}

// ---------------------------------------------------------------- K5: Kp·w_k for all G2 rows (coalesced QWt)
__launch_bounds__(128, 4)
__global__ void k_kp(const float* __restrict__ G2,
                     const float* __restrict__ QWt, const float* __restrict__ QB,
                     const float* __restrict__ MW,
                     float* __restrict__ KPWG)
{
  __shared__ __align__(16) float X[8][128];
  __shared__ float red[8][2];
  const int tid = threadIdx.x;
  const int base = blockIdx.x * 8;
  for (int o = tid; o < 1024; o += 128){
    int r = o >> 7, c = o & 127;
    X[r][c] = G2[(base + r)*128 + c];
  }
  __syncthreads();
  float acc[8];
  float bias = QB[tid];
  #pragma unroll
  for (int r = 0; r < 8; r++) acc[r] = bias;
  const float4* wp = (const float4*)QWt;
  #pragma unroll 4
  for (int g = 0; g < 32; g++){
    float4 wv = wp[g*128 + tid];
    int kk = 4*g;
    #pragma unroll
    for (int r = 0; r < 8; r++){
      float4 t4 = *(const float4*)(&X[r][kk]);
      acc[r] = fmaf(t4.x, wv.x, acc[r]);
      acc[r] = fmaf(t4.y, wv.y, acc[r]);
      acc[r] = fmaf(t4.z, wv.z, acc[r]);
      acc[r] = fmaf(t4.w, wv.w, acc[r]);
    }
  }
  const float wk = MW[128 + tid];
  const int lane = tid & 63, wv_ = tid >> 6;
  #pragma unroll
  for (int r = 0; r < 8; r++){
    float pv = fast_tanh(acc[r]) * wk;
    for (int off = 32; off; off >>= 1) pv += __shfl_down(pv, off);
    if (lane == 0) red[r][wv_] = pv;
  }
  __syncthreads();
  if (tid < 8) KPWG[base + tid] = red[tid][0] + red[tid][1];
}

// ---------------------------------------------------------------- K6: predict + output
__global__ void k_pred(const int* __restrict__ question,
                       const int* __restrict__ qci, const void* __restrict__ qcm,
                       const int* __restrict__ flags,
                       const float* __restrict__ EQ, const float* __restrict__ EC,
                       const float* __restrict__ QB, const float* __restrict__ MW,
                       const float* __restrict__ G2,
                       const int* __restrict__ IDX,
                       const float* __restrict__ KPWG,
                       void* __restrict__ outp)
{
  const int blk = blockIdx.x;
  const int t = blk >> 5, b = blk & 31;
  const int tid = threadIdx.x;               // 64
  __shared__ float hist[11][132];
  __shared__ float qcs[128];
  __shared__ float og[11];
  __shared__ float kpw[11];
  __shared__ int   idxs[10];
  __shared__ float kpw0s;
  const int qid = question[b*S_ + t + 1];
  const int bflag = flags[1];
  if (tid < 10) idxs[tid] = IDX[blk*10 + tid];
  __syncthreads();
  for (int o = tid; o < 11*128; o += 64){
    int k = o >> 7, c = o & 127;
    float v;
    if (k == 0) v = G2[blk*128 + c];
    else { int s = idxs[k-1]; v = (s == 0) ? 0.f : G2[(s*32 + b)*128 + c]; }
    hist[k][c] = v;
  }
  #pragma unroll
  for (int o = tid; o < 128; o += 64){
    float v = EQ[qid*128 + o];
    #pragma unroll
    for (int q = 0; q < 4; q++){
      if (readBool(qcm, qid*4 + q, bflag))
        v += EC[qci[qid*4 + q]*128 + o];
    }
    qcs[o] = v;
  }
  {
    float pv = fast_tanh(QB[tid])      * MW[128 + tid]
             + fast_tanh(QB[tid + 64]) * MW[128 + tid + 64];
    for (int off = 32; off; off >>= 1) pv += __shfl_down(pv, off);
    if (tid == 0) kpw0s = pv;
  }
  __syncthreads();
  if (tid < 11){
    float acc = 0.f;
    for (int c = 0; c < 128; c++) acc = fmaf(qcs[c], hist[tid][c], acc);
    og[tid] = acc;
    float v;
    if (tid == 0) v = KPWG[blk];
    else { int s = idxs[tid-1]; v = (s == 0) ? kpw0s : KPWG[s*32 + b]; }
    kpw[tid] = v;
  }
  __syncthreads();
  if (tid == 0){
    float tv[11];
    #pragma unroll
    for (int k = 0; k < 11; k++){
      int valid = (k == 0) || (idxs[k-1] < t);
      tv[k] = valid ? kpw[k] : NEGV;
    }
    float m = tv[0];
    #pragma unroll
    for (int k = 1; k < 11; k++) m = fmaxf(m, tv[k]);
    float den = 0.f, num = 0.f;
    #pragma unroll
    for (int k = 0; k < 11; k++){
      float e = __expf(tv[k] - m);
      den += e;
      num = fmaf(e, og[k], num);
    }
    float p = num / den;
    int col = (t == 0) ? 0 : (t + 1);
    if (flags[0]){
      ((float*)outp)[b*S_ + col] = p;
      if (t == 0) ((float*)outp)[b*S_ + 1] = 0.f;
    } else {
      ((u16*)outp)[b*S_ + col] = f2bf(p);
      if (t == 0) ((u16*)outp)[b*S_ + 1] = (u16)0;
    }
  }
}

// ---------------------------------------------------------------- launcher
extern "C" void kernel_launch(void* const* d_in, const int* in_sizes, int n_in,
                              void* d_out, int out_size, void* d_ws, size_t ws_size,
                              hipStream_t stream)
{
  (void)in_sizes; (void)n_in; (void)out_size; (void)ws_size;
  const int* question      = (const int*)d_in[0];
  const int* response      = (const int*)d_in[1];
  const void* maskp        = d_in[2];
  const int* q_neighbors   = (const int*)d_in[3];
  const int* s_neighbors   = (const int*)d_in[4];
  const int* q_concept_idx = (const int*)d_in[5];
  const void* q_concept_mask = d_in[6];

  static const int CN[NCVT] = {2560000,256000,256,98304,49152,384,384,49152,49152,
                               384,384,49152,384,16384,128,16384,128,16384,128,
                               256,1,4096,4096};
  CvtArgs ca;
  int off = 0;
  for (int i = 0; i < NCVT; i++){
    ca.s[i] = d_in[7 + i];
    ca.nreal[i] = CN[i];
    ca.off[i] = off;
    off += (CN[i] + 3) & ~3;
  }
  ca.off[NCVT] = off;
  const int total = off;

  char* ws = (char*)d_ws;
  size_t wo = 0;
  auto alloc = [&](size_t bytes) -> void* {
    void* p = ws + wo;
    wo = (wo + bytes + 255) & ~(size_t)255;
    return p;
  };
  int*   flags = (int*)  alloc(16);
  float* CVT   = (float*)alloc((size_t)total * 4);
  float* EQREC = (float*)alloc((size_t)B_*S_*D_*4);
  float* GI1   = (float*)alloc((size_t)T_*B_*384*4);
  float* GI2A  = (float*)alloc((size_t)T_*B_*384*4);
  float* H1ALL = (float*)alloc((size_t)T_*B_*D_*4);
  float* G2    = (float*)alloc((size_t)T_*B_*D_*4);
  int*   IDX   = (int*)  alloc((size_t)T_*B_*10*4);
  float* KPWG  = (float*)alloc((size_t)T_*B_*4);
  float* KHG   = (float*)alloc((size_t)B_*S_*D_*4);
  u16*   WHH1h = (u16*)  alloc(49152*2);
  u16*   WHH2h = (u16*)  alloc(49152*2);
  u32*   AWt   = (u32*)  alloc(24576*4);
  u32*   ALWt  = (u32*)  alloc(8192*4);
  u32*   WIH1t = (u32*)  alloc(49152*4);
  u32*   WIH2t = (u32*)  alloc(24576*4);
  float* QWt   = (float*)alloc(16384*4);

  const float* EQ   = CVT + ca.off[0];
  const float* EC   = CVT + ca.off[1];
  const float* ECOR = CVT + ca.off[2];
  const float* WIH1 = CVT + ca.off[3];
  const float* WHH1 = CVT + ca.off[4];
  const float* BIH1 = CVT + ca.off[5];
  const float* BHH1 = CVT + ca.off[6];
  const float* WIH2 = CVT + ca.off[7];
  const float* WHH2 = CVT + ca.off[8];
  const float* BIH2 = CVT + ca.off[9];
  const float* BHH2 = CVT + ca.off[10];
  const float* AW   = CVT + ca.off[11];
  const float* AB   = CVT + ca.off[12];
  const float* ALW  = CVT + ca.off[13];
  const float* ALB  = CVT + ca.off[14];
  const float* QW   = CVT + ca.off[15];
  const float* QB   = CVT + ca.off[16];
  const float* MW   = CVT + ca.off[19];
  const float* H1I  = CVT + ca.off[21];
  const float* H2I  = CVT + ca.off[22];

  k_sniff2<<<1, 256, 0, stream>>>((const u16*)d_in[7], (const unsigned char*)maskp, flags);
  k_cvt<<<(total + 255)/256, 256, 0, stream>>>(ca, flags, CVT);
  k_prep<<<192, 256, 0, stream>>>(WHH1, WHH2, AW, ALW, WIH1, WIH2, QW,
                                  WHH1h, WHH2h, AWt, ALWt, WIH1t, WIH2t, QWt);
  k_khg<<<(B_*S_*D_ + 255)/256, 256, 0, stream>>>(question, EQ, KHG);
  k_agg<<<B_*S_/2, 256, 0, stream>>>(question, q_neighbors, s_neighbors, EQ, EC,
                                     AWt, AB, ALWt, ALB, maskp, flags, EQREC);
  k_gi1<<<dim3(T_, 4), 384, 0, stream>>>(EQREC, response, ECOR, WIH1t, BIH1, GI1);
  k_topk<<<T_*B_, 64, 0, stream>>>(KHG, IDX);
  k_chain1<<<B_, 384, 0, stream>>>(GI1, WHH1h, BHH1, H1I, H1ALL);
  k_gi2<<<dim3(T_, 4), 384, 0, stream>>>(H1ALL, WIH2t, BIH2, GI2A);
  k_chain2<<<B_, 384, 0, stream>>>(GI2A, WHH2h, BHH2, H2I, G2);
  k_kp<<<T_*B_/8, 128, 0, stream>>>(G2, QWt, QB, MW, KPWG);
  k_pred<<<T_*B_, 64, 0, stream>>>(question, q_concept_idx, q_concept_mask, flags,
                                   EQ, EC, QB, MW, G2, IDX, KPWG, d_out);
}

// Round 16
// 638.199 us; speedup vs baseline: 2.6694x; 1.2076x over previous
//
#include <hip/hip_runtime.h>
#include <math.h>

typedef unsigned short u16;
typedef unsigned int   u32;
typedef __attribute__((ext_vector_type(2))) _Float16 half2_t;

#define B_   32
#define S_   200
#define D_   128
#define T_   199
#define NEGV (-1e30f)

__device__ __forceinline__ float bf2f(u16 u){
  union { u32 i; float f; } v; v.i = ((u32)u) << 16; return v.f;
}
__device__ __forceinline__ u16 f2bf(float f){
  union { float f; u32 i; } v; v.f = f;
  u32 x = v.i;
  return (u16)((x + 0x7fffu + ((x >> 16) & 1u)) >> 16);   // RNE
}
__device__ __forceinline__ u16 f2h(float x){
  union { _Float16 h; u16 u; } v; v.h = (_Float16)x; return v.u;
}
__device__ __forceinline__ float h2f(u16 u){
  union { u16 u; _Float16 h; } v; v.u = u; return (float)v.h;
}
__device__ __forceinline__ u32 pkh(float lo, float hi){
  return ((u32)f2h(hi) << 16) | f2h(lo);
}
__device__ __forceinline__ float dot2f(u32 w, u32 h, float acc){
#if __has_builtin(__builtin_amdgcn_fdot2)
  union { u32 u; half2_t h2; } a, b;
  a.u = w; b.u = h;
  return __builtin_amdgcn_fdot2(a.h2, b.h2, acc, false);
#else
  union { u32 u; _Float16 f[2]; } a, b;
  a.u = w; b.u = h;
  acc = fmaf((float)a.f[0], (float)b.f[0], acc);
  return fmaf((float)a.f[1], (float)b.f[1], acc);
#endif
}
__device__ __forceinline__ float fast_sigmoid(float x){ return 1.f/(1.f+__expf(-x)); }
__device__ __forceinline__ float fast_tanh(float x){
  float e = __expf(2.f*x);
  return 1.f - 2.f/(e + 1.f);
}

// bool storage modes: 0=int32, 1=u8, 2=bf16, 3=f32
__device__ __forceinline__ int readBool(const void* p, int i, int m){
  if (m == 0) return ((const int*)p)[i] != 0;
  if (m == 1) return ((const unsigned char*)p)[i] != 0;
  if (m == 2) return ((const u16*)p)[i] != 0;
  return ((const u32*)p)[i] != 0;
}

// ---------------------------------------------------------------- sniffer
__global__ void k_sniff2(const u16* __restrict__ embq_raw,
                         const unsigned char* __restrict__ mask_raw,
                         int* __restrict__ flags){
  __shared__ int bad, gt1, m4, b0;
  const int tid = threadIdx.x;
  if (tid == 0){ bad = 0; gt1 = 0; m4 = 0; b0 = 0; }
  __syncthreads();
  for (int i = tid; i < 512; i += 256){
    u16 u = embq_raw[i];
    if (u){ int e = (u >> 7) & 0xFF; if (e < 0x58 || e > 0x7F) atomicAdd(&bad, 1); }
  }
  for (int i = tid; i < 1024; i += 256){
    unsigned char c = mask_raw[i];
    if (c > 1) atomicAdd(&gt1, 1);
    if (c && (i & 3)) atomicAdd(&m4, 1);
    if (c && !(i & 3)) atomicAdd(&b0, 1);
  }
  __syncthreads();
  if (tid == 0){
    flags[0] = (bad >= 16) ? 1 : 0;
    flags[1] = gt1 ? (b0 ? 2 : 3) : (m4 ? 1 : 0);
  }
}

// ---------------------------------------------------------------- convert floats -> f32
#define NCVT 23
struct CvtArgs { const void* s[NCVT]; int off[NCVT+1]; int nreal[NCVT]; };

__global__ void k_cvt(CvtArgs a, const int* __restrict__ flags, float* __restrict__ dst){
  __shared__ int f;
  if (threadIdx.x == 0) f = flags[0];
  __syncthreads();
  int gid = blockIdx.x * 256 + threadIdx.x;
  if (gid >= a.off[NCVT]) return;
  int ai = 0;
  for (int i = 1; i < NCVT; i++) if (gid >= a.off[i]) ai = i;
  int i = gid - a.off[ai];
  float v = 0.f;
  if (i < a.nreal[ai])
    v = f ? ((const float*)a.s[ai])[i] : bf2f(((const u16*)a.s[ai])[i]);
  dst[gid] = v;
}

// ---------------------------------------------------------------- prep (transposed/coalesced weights)
__global__ void k_prep(const float* __restrict__ WHH1, const float* __restrict__ WHH2,
                       const float* __restrict__ AW,   const float* __restrict__ ALW,
                       const float* __restrict__ WIH1, const float* __restrict__ WIH2,
                       const float* __restrict__ QW,
                       u16* __restrict__ WHH1h, u16* __restrict__ WHH2h,
                       u32* __restrict__ AWt,   u32* __restrict__ ALWt,
                       u32* __restrict__ WIH1t, u32* __restrict__ WIH2t,
                       float* __restrict__ QWt)
{
  const int gid0 = blockIdx.x*256 + threadIdx.x;
  const int stride = gridDim.x*256;
  for (int g = gid0; g < 49152; g += stride){
    WHH1h[g] = f2h(WHH1[g]);
    WHH2h[g] = f2h(WHH2[g]);
  }
  for (int g = gid0; g < 24576; g += stride){
    int s = g >> 13, w = g & 8191;
    int k8 = w >> 9, r = w & 511, c = r >> 2, j = r & 3;
    const float* b = AW + s*16384 + c*128 + k8*8 + 2*j;
    AWt[g] = pkh(b[0], b[1]);
  }
  for (int g = gid0; g < 8192; g += stride){
    int k8 = g >> 9, r = g & 511, c = r >> 2, j = r & 3;
    const float* b = ALW + c*128 + k8*8 + 2*j;
    ALWt[g] = pkh(b[0], b[1]);
  }
  for (int g = gid0; g < 49152; g += stride){
    int k8 = g / 1536, r = g % 1536, c = r >> 2, j = r & 3;
    const float* b = WIH1 + c*256 + k8*8 + 2*j;
    WIH1t[g] = pkh(b[0], b[1]);
  }
  for (int g = gid0; g < 24576; g += stride){
    int k8 = g / 1536, r = g % 1536, c = r >> 2, j = r & 3;
    const float* b = WIH2 + c*128 + k8*8 + 2*j;
    WIH2t[g] = pkh(b[0], b[1]);
  }
  for (int g = gid0; g < 16384; g += stride){
    int k4 = g >> 9, r = g & 511, c = r >> 2, j = r & 3;
    QWt[g] = QW[c*128 + k4*4 + j];
  }
}

// ---------------------------------------------------------------- khg: K_hist pre-gather (coalesced)
__global__ void k_khg(const int* __restrict__ question,
                      const float* __restrict__ EQ,
                      float* __restrict__ KHG)
{
  int o = blockIdx.x*256 + threadIdx.x;
  if (o < B_*S_*D_){
    int row = o >> 7;
    KHG[o] = EQ[question[row]*128 + (o & 127)];
  }
}

// ---------------------------------------------------------------- khgt: per-b transpose K_hist
// KHGT[b][k][s] so topk lanes (spanning s) read coalesced. LDS tile with odd
// stride 129: staging (vary c) and transposed reads (vary s) both conflict-free.
__global__ void k_khgt(const float* __restrict__ KHG,
                       float* __restrict__ KHGT)
{
  __shared__ float tile[100*129];            // 51.6 KB
  const int b  = blockIdx.x;
  const int sg = blockIdx.y;                 // 2 groups of 100 rows
  const int s0 = sg*100;
  const int tid = threadIdx.x;               // 256
  for (int o = tid; o < 100*128; o += 256){
    int s = o >> 7, c = o & 127;
    tile[s*129 + c] = KHG[(b*S_ + s0 + s)*128 + c];
  }
  __syncthreads();
  for (int o = tid; o < 128*100; o += 256){
    int k = o / 100, s = o % 100;
    KHGT[((size_t)b*128 + k)*200 + s0 + s] = tile[s*129 + k];
  }
}

// ---------------------------------------------------------------- K1: hop aggregation (f16 dot2, coalesced Wt)
template<int ROWS>
__device__ __forceinline__ void agg_stage_h(const u16* __restrict__ tmph,
    const u32* __restrict__ Wt, const float* __restrict__ bg,
    u16* __restrict__ outh, int c)
{
  float bias = bg[c];
  float acc[ROWS];
  #pragma unroll
  for (int r = 0; r < ROWS; r++) acc[r] = bias;
  const uint4* wp = (const uint4*)Wt;
  if constexpr (ROWS <= 4){
    float acc2[ROWS];
    #pragma unroll
    for (int r = 0; r < ROWS; r++) acc2[r] = 0.f;
    #pragma unroll 4
    for (int g = 0; g < 16; g++){
      uint4 wv = wp[g*128 + c];
      #pragma unroll
      for (int r = 0; r < ROWS; r++){
        uint4 hv = *(const uint4*)(tmph + r*128 + g*8);
        acc[r]  = dot2f(wv.x, hv.x, acc[r]);
        acc2[r] = dot2f(wv.y, hv.y, acc2[r]);
        acc[r]  = dot2f(wv.z, hv.z, acc[r]);
        acc2[r] = dot2f(wv.w, hv.w, acc2[r]);
      }
    }
    #pragma unroll
    for (int r = 0; r < ROWS; r++)
      outh[r*128 + c] = f2h(fast_tanh(acc[r] + acc2[r]));
  } else {
    #pragma unroll 4
    for (int g = 0; g < 16; g++){
      uint4 wv = wp[g*128 + c];
      #pragma unroll
      for (int r = 0; r < ROWS; r++){
        uint4 hv = *(const uint4*)(tmph + r*128 + g*8);
        acc[r] = dot2f(wv.x, hv.x, acc[r]);
        acc[r] = dot2f(wv.y, hv.y, acc[r]);
        acc[r] = dot2f(wv.z, hv.z, acc[r]);
        acc[r] = dot2f(wv.w, hv.w, acc[r]);
      }
    }
    #pragma unroll
    for (int r = 0; r < ROWS; r++)
      outh[r*128 + c] = f2h(fast_tanh(acc[r]));
  }
}

__launch_bounds__(256, 4)
__global__ void k_agg(const int* __restrict__ question,
                      const int* __restrict__ q_neighbors,
                      const int* __restrict__ s_neighbors,
                      const float* __restrict__ EQ,
                      const float* __restrict__ EC,
                      const u32* __restrict__ AWt,
                      const float* __restrict__ AB,
                      const u32* __restrict__ ALWt,
                      const float* __restrict__ ALB,
                      const void* __restrict__ maskp,
                      const int* __restrict__ flags,
                      float* __restrict__ EQREC)
{
  __shared__ __align__(16) u16 e0h[2][128];
  __shared__ __align__(16) u16 e1h[2][512];
  __shared__ __align__(16) u16 e2h[2][2048];
  __shared__ __align__(16) u16 tmph[2][2048];
  __shared__ int nn1[2][4]; __shared__ int nn2[2][16]; __shared__ int nn3[2][64];
  const int tid  = threadIdx.x;
  const int c    = tid & 127;
  const int half = tid >> 7;
  const int bs   = blockIdx.x*2 + half;
  const int n0   = question[bs];
  u16* tp = tmph[half];

  if (c < 4) nn1[half][c] = q_neighbors[n0*4 + c];
  __syncthreads();
  if (c < 16) nn2[half][c] = s_neighbors[nn1[half][c>>2]*4 + (c&3)];
  __syncthreads();
  if (c < 64) nn3[half][c] = q_neighbors[nn2[half][c>>2]*4 + (c&3)];
  e0h[half][c] = f2h(EQ[n0*128 + c]);
  #pragma unroll
  for (int r = 0; r < 4; r++)  e1h[half][r*128 + c] = f2h(EC[nn1[half][r]*128 + c]);
  #pragma unroll 4
  for (int r = 0; r < 16; r++) e2h[half][r*128 + c] = f2h(EQ[nn2[half][r]*128 + c]);
  __syncthreads();

  auto fill_e0 = [&](){
    float v = 0.25f*(h2f(e1h[half][c]) + h2f(e1h[half][128+c])
                   + h2f(e1h[half][256+c]) + h2f(e1h[half][384+c]))
            + h2f(e0h[half][c]);
    tp[c] = f2h(v);
  };
  auto fill_e1 = [&](){
    #pragma unroll
    for (int r = 0; r < 4; r++){
      float v = 0.25f*(h2f(e2h[half][(4*r)*128+c])   + h2f(e2h[half][(4*r+1)*128+c])
                     + h2f(e2h[half][(4*r+2)*128+c]) + h2f(e2h[half][(4*r+3)*128+c]))
              + h2f(e1h[half][r*128 + c]);
      tp[r*128 + c] = f2h(v);
    }
  };

  fill_e0(); __syncthreads();
  agg_stage_h<1>(tp, AWt, AB, e0h[half], c); __syncthreads();
  fill_e1(); __syncthreads();
  agg_stage_h<4>(tp, AWt + 8192, AB + 128, e1h[half], c); __syncthreads();
  #pragma unroll 2
  for (int r = 0; r < 16; r++){
    float m = 0.25f*( EC[nn3[half][4*r]*128+c]   + EC[nn3[half][4*r+1]*128+c]
                    + EC[nn3[half][4*r+2]*128+c] + EC[nn3[half][4*r+3]*128+c] );
    tp[r*128 + c] = f2h(m + h2f(e2h[half][r*128 + c]));
  }
  __syncthreads();
  agg_stage_h<16>(tp, AWt + 16384, AB + 256, e2h[half], c); __syncthreads();
  fill_e0(); __syncthreads();
  agg_stage_h<1>(tp, AWt, AB, e0h[half], c); __syncthreads();
  fill_e1(); __syncthreads();
  agg_stage_h<4>(tp, AWt + 8192, AB + 128, e1h[half], c); __syncthreads();
  fill_e0(); __syncthreads();
  agg_stage_h<1>(tp, AWt, AB, e0h[half], c); __syncthreads();
  agg_stage_h<1>(e0h[half], ALWt, ALB, tp, c); __syncthreads();
  const int msk = readBool(maskp, bs, flags[1]);
  EQREC[bs*128 + c] = msk ? h2f(tp[c]) : EQ[n0*128 + c];
}

// ---------------------------------------------------------------- K2: gi1 precompute (K=256, f16 dot2, coalesced)
__launch_bounds__(384, 1)
__global__ void k_gi1(const float* __restrict__ EQREC,
                      const int* __restrict__ response,
                      const float* __restrict__ ECOR,
                      const u32* __restrict__ WIH1t,
                      const float* __restrict__ BIH1,
                      float* __restrict__ GI1)
{
  const int t  = blockIdx.x;
  const int bg = blockIdx.y;
  const int tid = threadIdx.x;
  __shared__ __align__(16) u16 X[8][256];
  for (int o = tid; o < 2048; o += 384){
    int bb = o >> 8, k = o & 255;
    int b = bg*8 + bb;
    float v = (k < 128) ? EQREC[(b*S_ + t)*128 + k]
                        : ECOR[response[b*S_ + t]*128 + (k - 128)];
    X[bb][k] = f2h(v);
  }
  __syncthreads();
  float bias = BIH1[tid];
  float acc[8];
  #pragma unroll
  for (int i = 0; i < 8; i++) acc[i] = bias;
  const uint4* wp = (const uint4*)WIH1t;
  #pragma unroll 4
  for (int g = 0; g < 32; g++){
    uint4 wv = wp[g*384 + tid];
    #pragma unroll
    for (int bb = 0; bb < 8; bb++){
      uint4 hv = *(const uint4*)(&X[bb][g*8]);
      acc[bb] = dot2f(wv.x, hv.x, acc[bb]);
      acc[bb] = dot2f(wv.y, hv.y, acc[bb]);
      acc[bb] = dot2f(wv.z, hv.z, acc[bb]);
      acc[bb] = dot2f(wv.w, hv.w, acc[bb]);
    }
  }
  #pragma unroll
  for (int bb = 0; bb < 8; bb++)
    GI1[(t*32 + bg*8 + bb)*384 + tid] = acc[bb];
}

// ---------------------------------------------------------------- K2b: gi2 precompute (K=128, f16 dot2, coalesced)
__launch_bounds__(384, 1)
__global__ void k_gi2(const float* __restrict__ H1ALL,
                      const u32* __restrict__ WIH2t,
                      const float* __restrict__ BIH2,
                      float* __restrict__ GI2)
{
  const int t  = blockIdx.x;
  const int bg = blockIdx.y;
  const int tid = threadIdx.x;
  __shared__ __align__(16) u16 X[8][128];
  for (int o = tid; o < 1024; o += 384){
    int bb = o >> 7, k = o & 127;
    int b = bg*8 + bb;
    X[bb][k] = f2h(H1ALL[(t*32 + b)*128 + k]);
  }
  __syncthreads();
  float bias = BIH2[tid];
  float acc[8];
  #pragma unroll
  for (int i = 0; i < 8; i++) acc[i] = bias;
  const uint4* wp = (const uint4*)WIH2t;
  #pragma unroll 4
  for (int g = 0; g < 16; g++){
    uint4 wv = wp[g*384 + tid];
    #pragma unroll
    for (int bb = 0; bb < 8; bb++){
      uint4 hv = *(const uint4*)(&X[bb][g*8]);
      acc[bb] = dot2f(wv.x, hv.x, acc[bb]);
      acc[bb] = dot2f(wv.y, hv.y, acc[bb]);
      acc[bb] = dot2f(wv.z, hv.z, acc[bb]);
      acc[bb] = dot2f(wv.w, hv.w, acc[bb]);
    }
  }
  #pragma unroll
  for (int bb = 0; bb < 8; bb++)
    GI2[(t*32 + bg*8 + bb)*384 + tid] = acc[bb];
}

// ---------------------------------------------------------------- K3: scores + top-10 (transposed K, coalesced, no tile)
// r15 lesson: 66KB tile -> 2 one-wave blocks/CU -> latency-bound (208 us,
// Occ 5.5%). With KHGT, lane s reads KHGT[k][s] coalesced; LDS is just qn
// -> high occupancy, no staging.
__global__ void k_topk(const float* __restrict__ KHG,
                       const float* __restrict__ KHGT,
                       int* __restrict__ IDX)
{
  const int blk = blockIdx.x;
  const int t = blk >> 5, b = blk & 31;
  const int tid = threadIdx.x;               // 64
  __shared__ __align__(16) float qn[128];
  for (int o = tid; o < 128; o += 64) qn[o] = KHG[((size_t)b*S_ + t + 1)*128 + o];
  __syncthreads();
  float acc[4] = {0.f, 0.f, 0.f, 0.f};
  const float* base = KHGT + (size_t)b*128*200;
  #pragma unroll 4
  for (int k = 0; k < 128; k++){
    const float qk = qn[k];
    const float* col = base + k*200 + tid;
    acc[0] = fmaf(col[0],   qk, acc[0]);
    acc[1] = fmaf(col[64],  qk, acc[1]);
    acc[2] = fmaf(col[128], qk, acc[2]);
    if (tid < 8) acc[3] = fmaf(col[192], qk, acc[3]);
  }
  float val[4]; int sv[4];
  #pragma unroll
  for (int i = 0; i < 4; i++){
    int s = tid + 64*i;
    sv[i] = s;
    float v = -3.0e38f;                      // sentinel (s >= 200)
    if (s < S_) v = (s < t) ? acc[i] : NEGV;
    val[i] = v;
  }
  for (int r = 0; r < 10; r++){
    float bv = -3.0e38f; int bi = 0x3fffffff;
    #pragma unroll
    for (int i = 0; i < 4; i++){
      if (val[i] > bv || (val[i] == bv && sv[i] < bi)){ bv = val[i]; bi = sv[i]; }
    }
    for (int off = 32; off; off >>= 1){
      float ov = __shfl_down(bv, off);
      int   oi = __shfl_down(bi, off);
      if (ov > bv || (ov == bv && oi < bi)){ bv = ov; bi = oi; }
    }
    int win = __shfl(bi, 0);
    if (tid == 0) IDX[blk*10 + r] = win;
    #pragma unroll
    for (int i = 0; i < 4; i++) if (sv[i] == win) val[i] = -3.0e38f;
  }
}

// ---------------------------------------------------------------- K4a: h1 chain (f16 dot2, batched groups of 4)
// r13 lesson: cross-block producer/consumer flags cost ~24 us/hop on MI355X
// -> keep the three chain-stage kernels separate (306 us total).
__launch_bounds__(384, 1)
__global__ void k_chain1(const float* __restrict__ GI1,
                         const u16* __restrict__ WHH1h,
                         const float* __restrict__ BHH1,
                         const float* __restrict__ H1I,
                         float* __restrict__ H1ALL)
{
  const int b = blockIdx.x;
  const int tid = threadIdx.x;
  __shared__ __align__(16) float h[128];
  __shared__ __align__(16) u16 hh[128];
  __shared__ float gh[384];
  if (tid < 128){ float v = H1I[b*128 + tid]; h[tid] = v; hh[tid] = f2h(v); }
  const float bias = BHH1[tid];
  u32 W[64];
  {
    const uint4* wp = (const uint4*)(WHH1h + tid*128);
    #pragma unroll
    for (int i = 0; i < 16; i++){
      uint4 v = wp[i];
      W[4*i] = v.x; W[4*i+1] = v.y; W[4*i+2] = v.z; W[4*i+3] = v.w;
    }
  }
  float cur[4][3] = {}, nxt[4][3] = {}, st[4] = {};
  if (tid < 128){
    #pragma unroll
    for (int i = 0; i < 4; i++){
      const float* gp = GI1 + (i*32 + b)*384;
      cur[i][0] = gp[tid]; cur[i][1] = gp[128+tid]; cur[i][2] = gp[256+tid];
    }
  }
  __syncthreads();
  for (int t0 = 0; t0 < T_; t0 += 4){
    if (tid < 128){
      #pragma unroll
      for (int i = 0; i < 4; i++){
        int tt = t0 + 4 + i;
        if (tt < T_){
          const float* gp = GI1 + (tt*32 + b)*384;
          nxt[i][0] = gp[tid]; nxt[i][1] = gp[128+tid]; nxt[i][2] = gp[256+tid];
        }
      }
    }
    #pragma unroll
    for (int ph = 0; ph < 4; ph++){
      if (t0 + ph >= T_) break;
      float a = bias, ab = 0.f;
      #pragma unroll
      for (int i = 0; i < 16; i++){
        uint4 hv = *(const uint4*)(hh + i*8);
        a  = dot2f(W[4*i],   hv.x, a);
        ab = dot2f(W[4*i+1], hv.y, ab);
        a  = dot2f(W[4*i+2], hv.z, a);
        ab = dot2f(W[4*i+3], hv.w, ab);
      }
      gh[tid] = a + ab;
      __syncthreads();
      if (tid < 128){
        float r = fast_sigmoid(cur[ph][0] + gh[tid]);
        float z = fast_sigmoid(cur[ph][1] + gh[128+tid]);
        float n = fast_tanh(cur[ph][2] + r*gh[256+tid]);
        float hn = (1.f - z)*n + z*h[tid];
        h[tid] = hn; hh[tid] = f2h(hn);
        st[ph] = hn;
      }
      __syncthreads();
    }
    if (tid < 128){
      #pragma unroll
      for (int ph = 0; ph < 4; ph++){
        int t = t0 + ph;
        if (t < T_) H1ALL[(t*32 + b)*128 + tid] = st[ph];
      }
      #pragma unroll
      for (int i = 0; i < 4; i++){
        cur[i][0] = nxt[i][0]; cur[i][1] = nxt[i][1]; cur[i][2] = nxt[i][2];
      }
    }
  }
}

// ---------------------------------------------------------------- K4b: h2/g2 chain (f16 dot2, batched)
__launch_bounds__(384, 1)
__global__ void k_chain2(const float* __restrict__ GI2,
                         const u16* __restrict__ WHH2h,
                         const float* __restrict__ BHH2,
                         const float* __restrict__ H2I,
                         float* __restrict__ G2)
{
  const int b = blockIdx.x;
  const int tid = threadIdx.x;
  __shared__ __align__(16) float h[128];
  __shared__ __align__(16) u16 hh[128];
  __shared__ float gh[384];
  if (tid < 128){ float v = H2I[b*128 + tid]; h[tid] = v; hh[tid] = f2h(v); }
  const float bias = BHH2[tid];
  u32 W[64];
  {
    const uint4* wp = (const uint4*)(WHH2h + tid*128);
    #pragma unroll
    for (int i = 0; i < 16; i++){
      uint4 v = wp[i];
      W[4*i] = v.x; W[4*i+1] = v.y; W[4*i+2] = v.z; W[4*i+3] = v.w;
    }
  }
  float cur[4][3] = {}, nxt[4][3] = {}, st[4] = {};
  if (tid < 128){
    #pragma unroll
    for (int i = 0; i < 4; i++){
      const float* gp = GI2 + (i*32 + b)*384;
      cur[i][0] = gp[tid]; cur[i][1] = gp[128+tid]; cur[i][2] = gp[256+tid];
    }
  }
  __syncthreads();
  for (int t0 = 0; t0 < T_; t0 += 4){
    if (tid < 128){
      #pragma unroll
      for (int i = 0; i < 4; i++){
        int tt = t0 + 4 + i;
        if (tt < T_){
          const float* gp = GI2 + (tt*32 + b)*384;
          nxt[i][0] = gp[tid]; nxt[i][1] = gp[128+tid]; nxt[i][2] = gp[256+tid];
        }
      }
    }
    #pragma unroll
    for (int ph = 0; ph < 4; ph++){
      const int t = t0 + ph;
      if (t >= T_) break;
      float a = bias, ab = 0.f;
      #pragma unroll
      for (int i = 0; i < 16; i++){
        uint4 hv = *(const uint4*)(hh + i*8);
        a  = dot2f(W[4*i],   hv.x, a);
        ab = dot2f(W[4*i+1], hv.y, ab);
        a  = dot2f(W[4*i+2], hv.z, a);
        ab = dot2f(W[4*i+3], hv.w, ab);
      }
      gh[tid] = a + ab;
      __syncthreads();
      if (tid < 128){
        float r2 = fast_sigmoid(cur[ph][0] + gh[tid]);
        float z2 = fast_sigmoid(cur[ph][1] + gh[128+tid]);
        float n2 = fast_tanh(cur[ph][2] + r2*gh[256+tid]);
        float g = (1.f - z2)*n2 + z2*h[tid];
        st[ph] = g;
        if (t > 0){ h[tid] = g; hh[tid] = f2h(g); }
      }
      __syncthreads();
    }
    if (tid < 128){
      #pragma unroll
      for (int ph = 0; ph < 4; ph++){
        int t = t0 + ph;
        if (t < T_) G2[(t*32 + b)*128 + tid] = st[ph];
      }
      #pragma unroll
      for (int i = 0; i < 4; i++){
        cur[i][0] = nxt[i][0]; cur[i][1] = nxt[i][1]; cur[i][2] = nxt[i][2];
      }
    }
  }
}

// ---------------------------------------------------------------- K5: Kp·w_k for all G2 rows (coalesced QWt)
__launch_bounds__(128, 4)
__global__ void k_kp(const float* __restrict__ G2,
                     const float* __restrict__ QWt, const float* __restrict__ QB,
                     const float* __restrict__ MW,
                     float* __restrict__ KPWG)
{
  __shared__ __align__(16) float X[8][128];
  __shared__ float red[8][2];
  const int tid = threadIdx.x;
  const int base = blockIdx.x * 8;
  for (int o = tid; o < 1024; o += 128){
    int r = o >> 7, c = o & 127;
    X[r][c] = G2[(base + r)*128 + c];
  }
  __syncthreads();
  float acc[8];
  float bias = QB[tid];
  #pragma unroll
  for (int r = 0; r < 8; r++) acc[r] = bias;
  const float4* wp = (const float4*)QWt;
  #pragma unroll 4
  for (int g = 0; g < 32; g++){
    float4 wv = wp[g*128 + tid];
    int kk = 4*g;
    #pragma unroll
    for (int r = 0; r < 8; r++){
      float4 t4 = *(const float4*)(&X[r][kk]);
      acc[r] = fmaf(t4.x, wv.x, acc[r]);
      acc[r] = fmaf(t4.y, wv.y, acc[r]);
      acc[r] = fmaf(t4.z, wv.z, acc[r]);
      acc[r] = fmaf(t4.w, wv.w, acc[r]);
    }
  }
  const float wk = MW[128 + tid];
  const int lane = tid & 63, wv_ = tid >> 6;
  #pragma unroll
  for (int r = 0; r < 8; r++){
    float pv = fast_tanh(acc[r]) * wk;
    for (int off = 32; off; off >>= 1) pv += __shfl_down(pv, off);
    if (lane == 0) red[r][wv_] = pv;
  }
  __syncthreads();
  if (tid < 8) KPWG[base + tid] = red[tid][0] + red[tid][1];
}

// ---------------------------------------------------------------- K6: predict + output
__global__ void k_pred(const int* __restrict__ question,
                       const int* __restrict__ qci, const void* __restrict__ qcm,
                       const int* __restrict__ flags,
                       const float* __restrict__ EQ, const float* __restrict__ EC,
                       const float* __restrict__ QB, const float* __restrict__ MW,
                       const float* __restrict__ G2,
                       const int* __restrict__ IDX,
                       const float* __restrict__ KPWG,
                       void* __restrict__ outp)
{
  const int blk = blockIdx.x;
  const int t = blk >> 5, b = blk & 31;
  const int tid = threadIdx.x;               // 64
  __shared__ float hist[11][132];
  __shared__ float qcs[128];
  __shared__ float og[11];
  __shared__ float kpw[11];
  __shared__ int   idxs[10];
  __shared__ float kpw0s;
  const int qid = question[b*S_ + t + 1];
  const int bflag = flags[1];
  if (tid < 10) idxs[tid] = IDX[blk*10 + tid];
  __syncthreads();
  for (int o = tid; o < 11*128; o += 64){
    int k = o >> 7, c = o & 127;
    float v;
    if (k == 0) v = G2[blk*128 + c];
    else { int s = idxs[k-1]; v = (s == 0) ? 0.f : G2[(s*32 + b)*128 + c]; }
    hist[k][c] = v;
  }
  #pragma unroll
  for (int o = tid; o < 128; o += 64){
    float v = EQ[qid*128 + o];
    #pragma unroll
    for (int q = 0; q < 4; q++){
      if (readBool(qcm, qid*4 + q, bflag))
        v += EC[qci[qid*4 + q]*128 + o];
    }
    qcs[o] = v;
  }
  {
    float pv = fast_tanh(QB[tid])      * MW[128 + tid]
             + fast_tanh(QB[tid + 64]) * MW[128 + tid + 64];
    for (int off = 32; off; off >>= 1) pv += __shfl_down(pv, off);
    if (tid == 0) kpw0s = pv;
  }
  __syncthreads();
  if (tid < 11){
    float acc = 0.f;
    for (int c = 0; c < 128; c++) acc = fmaf(qcs[c], hist[tid][c], acc);
    og[tid] = acc;
    float v;
    if (tid == 0) v = KPWG[blk];
    else { int s = idxs[tid-1]; v = (s == 0) ? kpw0s : KPWG[s*32 + b]; }
    kpw[tid] = v;
  }
  __syncthreads();
  if (tid == 0){
    float tv[11];
    #pragma unroll
    for (int k = 0; k < 11; k++){
      int valid = (k == 0) || (idxs[k-1] < t);
      tv[k] = valid ? kpw[k] : NEGV;
    }
    float m = tv[0];
    #pragma unroll
    for (int k = 1; k < 11; k++) m = fmaxf(m, tv[k]);
    float den = 0.f, num = 0.f;
    #pragma unroll
    for (int k = 0; k < 11; k++){
      float e = __expf(tv[k] - m);
      den += e;
      num = fmaf(e, og[k], num);
    }
    float p = num / den;
    int col = (t == 0) ? 0 : (t + 1);
    if (flags[0]){
      ((float*)outp)[b*S_ + col] = p;
      if (t == 0) ((float*)outp)[b*S_ + 1] = 0.f;
    } else {
      ((u16*)outp)[b*S_ + col] = f2bf(p);
      if (t == 0) ((u16*)outp)[b*S_ + 1] = (u16)0;
    }
  }
}

// ---------------------------------------------------------------- launcher
extern "C" void kernel_launch(void* const* d_in, const int* in_sizes, int n_in,
                              void* d_out, int out_size, void* d_ws, size_t ws_size,
                              hipStream_t stream)
{
  (void)in_sizes; (void)n_in; (void)out_size; (void)ws_size;
  const int* question      = (const int*)d_in[0];
  const int* response      = (const int*)d_in[1];
  const void* maskp        = d_in[2];
  const int* q_neighbors   = (const int*)d_in[3];
  const int* s_neighbors   = (const int*)d_in[4];
  const int* q_concept_idx = (const int*)d_in[5];
  const void* q_concept_mask = d_in[6];

  static const int CN[NCVT] = {2560000,256000,256,98304,49152,384,384,49152,49152,
                               384,384,49152,384,16384,128,16384,128,16384,128,
                               256,1,4096,4096};
  CvtArgs ca;
  int off = 0;
  for (int i = 0; i < NCVT; i++){
    ca.s[i] = d_in[7 + i];
    ca.nreal[i] = CN[i];
    ca.off[i] = off;
    off += (CN[i] + 3) & ~3;
  }
  ca.off[NCVT] = off;
  const int total = off;

  char* ws = (char*)d_ws;
  size_t wo = 0;
  auto alloc = [&](size_t bytes) -> void* {
    void* p = ws + wo;
    wo = (wo + bytes + 255) & ~(size_t)255;
    return p;
  };
  int*   flags = (int*)  alloc(16);
  float* CVT   = (float*)alloc((size_t)total * 4);
  float* EQREC = (float*)alloc((size_t)B_*S_*D_*4);
  float* GI1   = (float*)alloc((size_t)T_*B_*384*4);
  float* GI2A  = (float*)alloc((size_t)T_*B_*384*4);
  float* H1ALL = (float*)alloc((size_t)T_*B_*D_*4);
  float* G2    = (float*)alloc((size_t)T_*B_*D_*4);
  int*   IDX   = (int*)  alloc((size_t)T_*B_*10*4);
  float* KPWG  = (float*)alloc((size_t)T_*B_*4);
  float* KHG   = (float*)alloc((size_t)B_*S_*D_*4);
  float* KHGT  = (float*)alloc((size_t)B_*S_*D_*4);
  u16*   WHH1h = (u16*)  alloc(49152*2);
  u16*   WHH2h = (u16*)  alloc(49152*2);
  u32*   AWt   = (u32*)  alloc(24576*4);
  u32*   ALWt  = (u32*)  alloc(8192*4);
  u32*   WIH1t = (u32*)  alloc(49152*4);
  u32*   WIH2t = (u32*)  alloc(24576*4);
  float* QWt   = (float*)alloc(16384*4);

  const float* EQ   = CVT + ca.off[0];
  const float* EC   = CVT + ca.off[1];
  const float* ECOR = CVT + ca.off[2];
  const float* WIH1 = CVT + ca.off[3];
  const float* WHH1 = CVT + ca.off[4];
  const float* BIH1 = CVT + ca.off[5];
  const float* BHH1 = CVT + ca.off[6];
  const float* WIH2 = CVT + ca.off[7];
  const float* WHH2 = CVT + ca.off[8];
  const float* BIH2 = CVT + ca.off[9];
  const float* BHH2 = CVT + ca.off[10];
  const float* AW   = CVT + ca.off[11];
  const float* AB   = CVT + ca.off[12];
  const float* ALW  = CVT + ca.off[13];
  const float* ALB  = CVT + ca.off[14];
  const float* QW   = CVT + ca.off[15];
  const float* QB   = CVT + ca.off[16];
  const float* MW   = CVT + ca.off[19];
  const float* H1I  = CVT + ca.off[21];
  const float* H2I  = CVT + ca.off[22];

  k_sniff2<<<1, 256, 0, stream>>>((const u16*)d_in[7], (const unsigned char*)maskp, flags);
  k_cvt<<<(total + 255)/256, 256, 0, stream>>>(ca, flags, CVT);
  k_prep<<<192, 256, 0, stream>>>(WHH1, WHH2, AW, ALW, WIH1, WIH2, QW,
                                  WHH1h, WHH2h, AWt, ALWt, WIH1t, WIH2t, QWt);
  k_khg<<<(B_*S_*D_ + 255)/256, 256, 0, stream>>>(question, EQ, KHG);
  k_khgt<<<dim3(B_, 2), 256, 0, stream>>>(KHG, KHGT);
  k_agg<<<B_*S_/2, 256, 0, stream>>>(question, q_neighbors, s_neighbors, EQ, EC,
                                     AWt, AB, ALWt, ALB, maskp, flags, EQREC);
  k_gi1<<<dim3(T_, 4), 384, 0, stream>>>(EQREC, response, ECOR, WIH1t, BIH1, GI1);
  k_topk<<<T_*B_, 64, 0, stream>>>(KHG, KHGT, IDX);
  k_chain1<<<B_, 384, 0, stream>>>(GI1, WHH1h, BHH1, H1I, H1ALL);
  k_gi2<<<dim3(T_, 4), 384, 0, stream>>>(H1ALL, WIH2t, BIH2, GI2A);
  k_chain2<<<B_, 384, 0, stream>>>(GI2A, WHH2h, BHH2, H2I, G2);
  k_kp<<<T_*B_/8, 128, 0, stream>>>(G2, QWt, QB, MW, KPWG);
  k_pred<<<T_*B_, 64, 0, stream>>>(question, q_concept_idx, q_concept_mask, flags,
                                   EQ, EC, QB, MW, G2, IDX, KPWG, d_out);
}